// Round 1
// baseline (2326.165 us; speedup 1.0000x reference)
//
#include <hip/hip_runtime.h>

#define BN_EPS 1e-5f

// ---------------------------------------------------------------------------
// Scatter-add aggregation: agg[dst] += ew * x[src]
// One wave (64 lanes) per edge; lanes span the feature dim.
// ---------------------------------------------------------------------------
__global__ __launch_bounds__(256) void scatter_k128(
    const float* __restrict__ x, const int* __restrict__ src,
    const int* __restrict__ dst, const float* __restrict__ ew,
    float* __restrict__ agg, int E)
{
    int gid  = blockIdx.x * blockDim.x + threadIdx.x;
    int wave = gid >> 6;
    int lane = gid & 63;
    int nw   = (gridDim.x * blockDim.x) >> 6;
    for (int e = wave; e < E; e += nw) {
        int s = src[e], d = dst[e];
        float w = ew[e];
        const float2 v = *reinterpret_cast<const float2*>(x + (size_t)s * 128 + lane * 2);
        float* ap = agg + (size_t)d * 128 + lane * 2;
        atomicAdd(ap,     v.x * w);
        atomicAdd(ap + 1, v.y * w);
    }
}

__global__ __launch_bounds__(256) void scatter_k64(
    const float* __restrict__ x, const int* __restrict__ src,
    const int* __restrict__ dst, const float* __restrict__ ew,
    float* __restrict__ agg, int E)
{
    int gid  = blockIdx.x * blockDim.x + threadIdx.x;
    int wave = gid >> 6;
    int lane = gid & 63;
    int nw   = (gridDim.x * blockDim.x) >> 6;
    for (int e = wave; e < E; e += nw) {
        int s = src[e], d = dst[e];
        float w = ew[e];
        float v = x[(size_t)s * 64 + lane];
        atomicAdd(agg + (size_t)d * 64 + lane, v * w);
    }
}

// ---------------------------------------------------------------------------
// Fused GIN MLP: h2 = ((1+eps)*x + agg) @ Wa + ba -> relu -> @ Wb + bb
// Also accumulates per-feature sum / sumsq for BN into stats[0:64]/[64:128].
// One wave per node row; lane = output feature. W matrices staged in LDS.
// ---------------------------------------------------------------------------
template<int F>
__global__ __launch_bounds__(256) void mlp_kernel(
    const float* __restrict__ xin, const float* __restrict__ agg,
    const float* __restrict__ epsp,
    const float* __restrict__ Wa, const float* __restrict__ ba,
    const float* __restrict__ Wb, const float* __restrict__ bb,
    float* __restrict__ h2, float* __restrict__ stats, int N)
{
    __shared__ float sWa[F * 64];
    __shared__ float sWb[64 * 64];
    __shared__ float rowbuf[4][F];
    __shared__ float mid[4][64];
    __shared__ float red[2][4][64];

    for (int i = threadIdx.x; i < F * 64; i += 256) sWa[i] = Wa[i];
    for (int i = threadIdx.x; i < 64 * 64; i += 256) sWb[i] = Wb[i];
    __syncthreads();

    const float eps1 = 1.0f + epsp[0];
    const int wid  = threadIdx.x >> 6;
    const int lane = threadIdx.x & 63;
    const float ba_l = ba[lane];
    const float bb_l = bb[lane];

    int wglobal = (blockIdx.x * 256 + threadIdx.x) >> 6;
    int nw      = (gridDim.x * 256) >> 6;

    float lsum = 0.f, lsq = 0.f;
    for (int r = wglobal; r < N; r += nw) {
        const float* xr = xin + (size_t)r * F;
        const float* ar = agg + (size_t)r * F;
        #pragma unroll
        for (int k = lane; k < F; k += 64)
            rowbuf[wid][k] = fmaf(eps1, xr[k], ar[k]);

        float acc = ba_l;
        #pragma unroll
        for (int k = 0; k < F; k += 4) {
            float4 rv = *reinterpret_cast<const float4*>(&rowbuf[wid][k]);
            acc = fmaf(rv.x, sWa[(k + 0) * 64 + lane], acc);
            acc = fmaf(rv.y, sWa[(k + 1) * 64 + lane], acc);
            acc = fmaf(rv.z, sWa[(k + 2) * 64 + lane], acc);
            acc = fmaf(rv.w, sWa[(k + 3) * 64 + lane], acc);
        }
        acc = fmaxf(acc, 0.f);
        mid[wid][lane] = acc;

        float acc2 = bb_l;
        #pragma unroll
        for (int k = 0; k < 64; k += 4) {
            float4 mv = *reinterpret_cast<const float4*>(&mid[wid][k]);
            acc2 = fmaf(mv.x, sWb[(k + 0) * 64 + lane], acc2);
            acc2 = fmaf(mv.y, sWb[(k + 1) * 64 + lane], acc2);
            acc2 = fmaf(mv.z, sWb[(k + 2) * 64 + lane], acc2);
            acc2 = fmaf(mv.w, sWb[(k + 3) * 64 + lane], acc2);
        }
        h2[(size_t)r * 64 + lane] = acc2;
        lsum += acc2;
        lsq  += acc2 * acc2;
    }

    red[0][wid][lane] = lsum;
    red[1][wid][lane] = lsq;
    __syncthreads();
    if (wid == 0) {
        float s = red[0][0][lane] + red[0][1][lane] + red[0][2][lane] + red[0][3][lane];
        float q = red[1][0][lane] + red[1][1][lane] + red[1][2][lane] + red[1][3][lane];
        atomicAdd(&stats[lane],      s);
        atomicAdd(&stats[64 + lane], q);
    }
}

// ---------------------------------------------------------------------------
// BN finalize: scale/shift from accumulated sums.  ab[0:64]=a, ab[64:128]=b
// ---------------------------------------------------------------------------
__global__ void bn_finalize(const float* __restrict__ stats,
                            const float* __restrict__ g, const float* __restrict__ be,
                            float* __restrict__ ab, int N)
{
    int l = threadIdx.x;
    float invN = 1.0f / (float)N;
    float mean = stats[l] * invN;
    float var  = stats[64 + l] * invN - mean * mean;
    float a = g[l] * rsqrtf(var + BN_EPS);
    ab[l]      = a;
    ab[64 + l] = be[l] - mean * a;
}

// ---------------------------------------------------------------------------
// BN apply (+ReLU, optional residual):  out = [res +] relu(h2*a + b)
// ---------------------------------------------------------------------------
template<int RES>
__global__ __launch_bounds__(256) void bn_apply(
    const float* __restrict__ h2, const float* __restrict__ ab,
    const float* __restrict__ res, float* __restrict__ out, int n4)
{
    int i = blockIdx.x * blockDim.x + threadIdx.x;
    int stride = gridDim.x * blockDim.x;
    for (; i < n4; i += stride) {
        float4 v = reinterpret_cast<const float4*>(h2)[i];
        int l0 = (i * 4) & 63;
        float4 o;
        o.x = fmaxf(fmaf(v.x, ab[l0 + 0], ab[64 + l0 + 0]), 0.f);
        o.y = fmaxf(fmaf(v.y, ab[l0 + 1], ab[64 + l0 + 1]), 0.f);
        o.z = fmaxf(fmaf(v.z, ab[l0 + 2], ab[64 + l0 + 2]), 0.f);
        o.w = fmaxf(fmaf(v.w, ab[l0 + 3], ab[64 + l0 + 3]), 0.f);
        if (RES) {
            float4 rv = reinterpret_cast<const float4*>(res)[i];
            o.x += rv.x; o.y += rv.y; o.z += rv.z; o.w += rv.w;
        }
        reinterpret_cast<float4*>(out)[i] = o;
    }
}

// ---------------------------------------------------------------------------
extern "C" void kernel_launch(void* const* d_in, const int* in_sizes, int n_in,
                              void* d_out, int out_size, void* d_ws, size_t ws_size,
                              hipStream_t stream)
{
    const float* x    = (const float*)d_in[0];
    const int*   ei   = (const int*)  d_in[1];
    const float* ew   = (const float*)d_in[2];
    const float* eps1 = (const float*)d_in[3];
    const float* W1a  = (const float*)d_in[4];
    const float* b1a  = (const float*)d_in[5];
    const float* W1b  = (const float*)d_in[6];
    const float* b1b  = (const float*)d_in[7];
    const float* g1   = (const float*)d_in[8];
    const float* be1  = (const float*)d_in[9];
    const float* epss = (const float*)d_in[10];
    const float* Wsa  = (const float*)d_in[11];
    const float* bsa  = (const float*)d_in[12];
    const float* Wsb  = (const float*)d_in[13];
    const float* bsb  = (const float*)d_in[14];
    const float* gs   = (const float*)d_in[15];
    const float* bes  = (const float*)d_in[16];

    const int N   = in_sizes[0] / 128;
    const int E   = in_sizes[2];
    const int Lm1 = in_sizes[10];
    const int* src  = ei;
    const int* dstp = ei + E;

    char*  ws    = (char*)d_ws;
    float* agg   = (float*)ws;                                          // N*128 f32
    float* hA    = (float*)(ws + (size_t)N * 128 * 4);                  // N*64 f32
    float* stats = (float*)(ws + (size_t)N * 128 * 4 + (size_t)N * 64 * 4); // 128 f32
    float* ab    = stats + 128;                                          // 128 f32
    float* outp  = (float*)d_out;
    float* h2b   = agg + (size_t)N * 64;  // layers 2+: h2 scratch (2nd half of agg region)

    const int n4 = N * 64 / 4;

    // ---- layer 1 (F=128 -> 64) ----
    hipMemsetAsync(agg,   0, (size_t)N * 128 * 4, stream);
    hipMemsetAsync(stats, 0, 128 * 4, stream);
    scatter_k128<<<4096, 256, 0, stream>>>(x, src, dstp, ew, agg, E);
    mlp_kernel<128><<<2048, 256, 0, stream>>>(x, agg, eps1, W1a, b1a, W1b, b1b,
                                              outp /*h2 scratch*/, stats, N);
    bn_finalize<<<1, 64, 0, stream>>>(stats, g1, be1, ab, N);
    float* h1dst = (Lm1 > 0) ? hA : outp;
    bn_apply<0><<<2048, 256, 0, stream>>>(outp, ab, nullptr, h1dst, n4);

    // ---- layers 2..L (F=64 -> 64, residual) ----
    const float* hin = hA;
    for (int i = 0; i < Lm1; ++i) {
        hipMemsetAsync(agg,   0, (size_t)N * 64 * 4, stream);
        hipMemsetAsync(stats, 0, 128 * 4, stream);
        scatter_k64<<<4096, 256, 0, stream>>>(hin, src, dstp, ew, agg, E);
        mlp_kernel<64><<<2048, 256, 0, stream>>>(hin, agg, epss + i,
                                                 Wsa + (size_t)i * 64 * 64, bsa + (size_t)i * 64,
                                                 Wsb + (size_t)i * 64 * 64, bsb + (size_t)i * 64,
                                                 h2b, stats, N);
        bn_finalize<<<1, 64, 0, stream>>>(stats, gs + (size_t)i * 64, bes + (size_t)i * 64, ab, N);
        bn_apply<1><<<2048, 256, 0, stream>>>(h2b, ab, hin, outp, n4);
        hin = outp;
    }
}

// Round 2
// 1314.616 us; speedup vs baseline: 1.7695x; 1.7695x over previous
//
#include <hip/hip_runtime.h>

#define BN_EPS 1e-5f

// ===========================================================================
// CSR construction (by dst): histogram -> single-block scan -> bucket fill
// ===========================================================================
__global__ __launch_bounds__(256) void hist_kernel(
    const int* __restrict__ dst, int* __restrict__ deg, int E)
{
    int i = blockIdx.x * blockDim.x + threadIdx.x;
    int stride = gridDim.x * blockDim.x;
    for (; i < E; i += stride) atomicAdd(&deg[dst[i]], 1);
}

__global__ __launch_bounds__(1024) void scan_kernel(
    const int* __restrict__ deg, int* __restrict__ row_start,
    int* __restrict__ cursor, int N, int E)
{
    __shared__ int part[1024];
    int t = threadIdx.x;
    int chunk = (N + 1023) >> 10;
    int lo = t * chunk;
    int hi = min(lo + chunk, N);
    int s = 0;
    for (int i = lo; i < hi; ++i) s += deg[i];
    part[t] = s;
    __syncthreads();
    for (int off = 1; off < 1024; off <<= 1) {
        int v = (t >= off) ? part[t - off] : 0;
        __syncthreads();
        part[t] += v;
        __syncthreads();
    }
    int run = (t > 0) ? part[t - 1] : 0;
    for (int i = lo; i < hi; ++i) {
        row_start[i] = run;
        cursor[i]    = run;
        run += deg[i];
    }
    if (t == 1023) row_start[N] = E;
}

__global__ __launch_bounds__(256) void fill_kernel(
    const int* __restrict__ src, const int* __restrict__ dst,
    const float* __restrict__ ew, int* __restrict__ cursor,
    uint2* __restrict__ einfo, int E)
{
    int i = blockIdx.x * blockDim.x + threadIdx.x;
    int stride = gridDim.x * blockDim.x;
    for (; i < E; i += stride) {
        int d = dst[i];
        int pos = atomicAdd(&cursor[d], 1);
        uint2 p;
        p.x = (unsigned)src[i];
        p.y = __float_as_uint(ew[i]);
        einfo[pos] = p;
    }
}

// ===========================================================================
// Fused GIN layer: in-register CSR gather-aggregate -> MLP -> BN-stats accum
//   h = (1+eps)*x[r] + sum_j w_j * x[src_j]
//   h2 = relu(h @ Wa + ba) @ Wb + bb     (h2 written; BN applied later)
// One wave per node row; lane = output feature. Weights staged in LDS.
// ===========================================================================
template<int F>
__global__ __launch_bounds__(256) void gin_layer_kernel(
    const float* __restrict__ xin,
    const int* __restrict__ row_start,
    const uint2* __restrict__ einfo,
    const float* __restrict__ epsp,
    const float* __restrict__ Wa, const float* __restrict__ ba,
    const float* __restrict__ Wb, const float* __restrict__ bb,
    float* __restrict__ h2, float* __restrict__ stats, int N)
{
    __shared__ float sWa[F * 64];
    __shared__ float sWb[64 * 64];
    __shared__ float rowbuf[4][F];
    __shared__ float red[2][4][64];

    for (int i = threadIdx.x; i < F * 64; i += 256) sWa[i] = Wa[i];
    for (int i = threadIdx.x; i < 64 * 64; i += 256) sWb[i] = Wb[i];
    __syncthreads();

    const float eps1 = 1.0f + epsp[0];
    const int wid  = threadIdx.x >> 6;
    const int lane = threadIdx.x & 63;
    const float ba_l = ba[lane];
    const float bb_l = bb[lane];

    int wglobal = (blockIdx.x * 256 + threadIdx.x) >> 6;
    int nw      = (gridDim.x * 256) >> 6;

    float lsum = 0.f, lsq = 0.f;
    for (int r = wglobal; r < N; r += nw) {
        const int rs = row_start[r];
        const int re = row_start[r + 1];

        if (F == 128) {
            float aA0 = 0.f, aA1 = 0.f, aB0 = 0.f, aB1 = 0.f;
            int j = rs;
            for (; j + 2 <= re; j += 2) {
                uint2 p0 = einfo[j], p1 = einfo[j + 1];
                float w0 = __uint_as_float(p0.y);
                float w1 = __uint_as_float(p1.y);
                float2 v0 = *reinterpret_cast<const float2*>(
                    xin + (size_t)p0.x * 128 + lane * 2);
                float2 v1 = *reinterpret_cast<const float2*>(
                    xin + (size_t)p1.x * 128 + lane * 2);
                aA0 = fmaf(w0, v0.x, aA0); aA1 = fmaf(w0, v0.y, aA1);
                aB0 = fmaf(w1, v1.x, aB0); aB1 = fmaf(w1, v1.y, aB1);
            }
            if (j < re) {
                uint2 p0 = einfo[j];
                float w0 = __uint_as_float(p0.y);
                float2 v0 = *reinterpret_cast<const float2*>(
                    xin + (size_t)p0.x * 128 + lane * 2);
                aA0 = fmaf(w0, v0.x, aA0); aA1 = fmaf(w0, v0.y, aA1);
            }
            float2 xv = *reinterpret_cast<const float2*>(
                xin + (size_t)r * 128 + lane * 2);
            rowbuf[wid][lane * 2]     = fmaf(eps1, xv.x, aA0 + aB0);
            rowbuf[wid][lane * 2 + 1] = fmaf(eps1, xv.y, aA1 + aB1);
        } else {
            float aA = 0.f, aB = 0.f;
            int j = rs;
            for (; j + 2 <= re; j += 2) {
                uint2 p0 = einfo[j], p1 = einfo[j + 1];
                float w0 = __uint_as_float(p0.y);
                float w1 = __uint_as_float(p1.y);
                float v0 = xin[(size_t)p0.x * 64 + lane];
                float v1 = xin[(size_t)p1.x * 64 + lane];
                aA = fmaf(w0, v0, aA);
                aB = fmaf(w1, v1, aB);
            }
            if (j < re) {
                uint2 p0 = einfo[j];
                aA = fmaf(__uint_as_float(p0.y), xin[(size_t)p0.x * 64 + lane], aA);
            }
            rowbuf[wid][lane] = fmaf(eps1, xin[(size_t)r * 64 + lane], aA + aB);
        }

        // ---- MLP: lane = output feature ----
        float acc = ba_l;
        #pragma unroll
        for (int k = 0; k < F; k += 4) {
            float4 rv = *reinterpret_cast<const float4*>(&rowbuf[wid][k]);
            acc = fmaf(rv.x, sWa[(k + 0) * 64 + lane], acc);
            acc = fmaf(rv.y, sWa[(k + 1) * 64 + lane], acc);
            acc = fmaf(rv.z, sWa[(k + 2) * 64 + lane], acc);
            acc = fmaf(rv.w, sWa[(k + 3) * 64 + lane], acc);
        }
        acc = fmaxf(acc, 0.f);
        rowbuf[wid][lane] = acc;   // reuse first 64 floats as mid buffer

        float acc2 = bb_l;
        #pragma unroll
        for (int k = 0; k < 64; k += 4) {
            float4 mv = *reinterpret_cast<const float4*>(&rowbuf[wid][k]);
            acc2 = fmaf(mv.x, sWb[(k + 0) * 64 + lane], acc2);
            acc2 = fmaf(mv.y, sWb[(k + 1) * 64 + lane], acc2);
            acc2 = fmaf(mv.z, sWb[(k + 2) * 64 + lane], acc2);
            acc2 = fmaf(mv.w, sWb[(k + 3) * 64 + lane], acc2);
        }
        h2[(size_t)r * 64 + lane] = acc2;
        lsum += acc2;
        lsq  += acc2 * acc2;
    }

    red[0][wid][lane] = lsum;
    red[1][wid][lane] = lsq;
    __syncthreads();
    if (wid == 0) {
        float s = red[0][0][lane] + red[0][1][lane] + red[0][2][lane] + red[0][3][lane];
        float q = red[1][0][lane] + red[1][1][lane] + red[1][2][lane] + red[1][3][lane];
        atomicAdd(&stats[lane],      s);
        atomicAdd(&stats[64 + lane], q);
    }
}

// ===========================================================================
// BN finalize + apply
// ===========================================================================
__global__ void bn_finalize(const float* __restrict__ stats,
                            const float* __restrict__ g, const float* __restrict__ be,
                            float* __restrict__ ab, int N)
{
    int l = threadIdx.x;
    float invN = 1.0f / (float)N;
    float mean = stats[l] * invN;
    float var  = stats[64 + l] * invN - mean * mean;
    float a = g[l] * rsqrtf(var + BN_EPS);
    ab[l]      = a;
    ab[64 + l] = be[l] - mean * a;
}

template<int RES>
__global__ __launch_bounds__(256) void bn_apply(
    const float* __restrict__ h2, const float* __restrict__ ab,
    const float* __restrict__ res, float* __restrict__ out, int n4)
{
    int i = blockIdx.x * blockDim.x + threadIdx.x;
    int stride = gridDim.x * blockDim.x;
    for (; i < n4; i += stride) {
        float4 v = reinterpret_cast<const float4*>(h2)[i];
        int l0 = (i * 4) & 63;
        float4 o;
        o.x = fmaxf(fmaf(v.x, ab[l0 + 0], ab[64 + l0 + 0]), 0.f);
        o.y = fmaxf(fmaf(v.y, ab[l0 + 1], ab[64 + l0 + 1]), 0.f);
        o.z = fmaxf(fmaf(v.z, ab[l0 + 2], ab[64 + l0 + 2]), 0.f);
        o.w = fmaxf(fmaf(v.w, ab[l0 + 3], ab[64 + l0 + 3]), 0.f);
        if (RES) {
            float4 rv = reinterpret_cast<const float4*>(res)[i];
            o.x += rv.x; o.y += rv.y; o.z += rv.z; o.w += rv.w;
        }
        reinterpret_cast<float4*>(out)[i] = o;
    }
}

// ===========================================================================
extern "C" void kernel_launch(void* const* d_in, const int* in_sizes, int n_in,
                              void* d_out, int out_size, void* d_ws, size_t ws_size,
                              hipStream_t stream)
{
    const float* x    = (const float*)d_in[0];
    const int*   ei   = (const int*)  d_in[1];
    const float* ew   = (const float*)d_in[2];
    const float* eps1 = (const float*)d_in[3];
    const float* W1a  = (const float*)d_in[4];
    const float* b1a  = (const float*)d_in[5];
    const float* W1b  = (const float*)d_in[6];
    const float* b1b  = (const float*)d_in[7];
    const float* g1   = (const float*)d_in[8];
    const float* be1  = (const float*)d_in[9];
    const float* epss = (const float*)d_in[10];
    const float* Wsa  = (const float*)d_in[11];
    const float* bsa  = (const float*)d_in[12];
    const float* Wsb  = (const float*)d_in[13];
    const float* bsb  = (const float*)d_in[14];
    const float* gs   = (const float*)d_in[15];
    const float* bes  = (const float*)d_in[16];

    const int N   = in_sizes[0] / 128;
    const int E   = in_sizes[2];
    const int Lm1 = in_sizes[10];
    const int* src  = ei;
    const int* dstp = ei + E;

    // ---- workspace layout ----
    char* ws = (char*)d_ws;
    size_t off = 0;
    uint2* einfo = (uint2*)(ws + off);          off += (size_t)E * 8;
    float* hA    = (float*)(ws + off);          off += (size_t)N * 64 * 4;
    float* h2b   = (float*)(ws + off);          off += (size_t)N * 64 * 4;
    int*   deg   = (int*)  (ws + off);          off += (size_t)N * 4;
    int*   row_start = (int*)(ws + off);        off += (size_t)(N + 1) * 4;
    int*   cursor    = (int*)(ws + off);        off += (size_t)N * 4;
    float* stats = (float*)(ws + off);          off += 128 * 4;
    float* ab    = (float*)(ws + off);
    float* outp  = (float*)d_out;

    const int n4 = N * 64 / 4;

    // ---- build CSR by dst (once per call, reused by all layers) ----
    hipMemsetAsync(deg, 0, (size_t)N * 4, stream);
    hist_kernel<<<1024, 256, 0, stream>>>(dstp, deg, E);
    scan_kernel<<<1, 1024, 0, stream>>>(deg, row_start, cursor, N, E);
    fill_kernel<<<1024, 256, 0, stream>>>(src, dstp, ew, cursor, einfo, E);

    // ---- layer 1 (F=128 -> 64) ----
    hipMemsetAsync(stats, 0, 128 * 4, stream);
    gin_layer_kernel<128><<<2048, 256, 0, stream>>>(
        x, row_start, einfo, eps1, W1a, b1a, W1b, b1b,
        outp /*h2 scratch*/, stats, N);
    bn_finalize<<<1, 64, 0, stream>>>(stats, g1, be1, ab, N);
    float* h1dst = (Lm1 > 0) ? hA : outp;
    bn_apply<0><<<2048, 256, 0, stream>>>(outp, ab, nullptr, h1dst, n4);

    // ---- layers 2..L (F=64 -> 64, residual) ----
    const float* hin = hA;
    for (int i = 0; i < Lm1; ++i) {
        hipMemsetAsync(stats, 0, 128 * 4, stream);
        gin_layer_kernel<64><<<2048, 256, 0, stream>>>(
            hin, row_start, einfo, epss + i,
            Wsa + (size_t)i * 64 * 64, bsa + (size_t)i * 64,
            Wsb + (size_t)i * 64 * 64, bsb + (size_t)i * 64,
            h2b, stats, N);
        bn_finalize<<<1, 64, 0, stream>>>(stats, gs + (size_t)i * 64, bes + (size_t)i * 64, ab, N);
        bn_apply<1><<<2048, 256, 0, stream>>>(h2b, ab, hin, outp, n4);
        hin = outp;
    }
}

// Round 3
// 1048.476 us; speedup vs baseline: 2.2186x; 1.2538x over previous
//
#include <hip/hip_runtime.h>

#define BN_EPS 1e-5f

// ===========================================================================
// CSR construction (by dst): histogram -> single-block scan -> bucket fill
// ===========================================================================
__global__ __launch_bounds__(256) void hist_kernel(
    const int* __restrict__ dst, int* __restrict__ deg, int E)
{
    int i = blockIdx.x * blockDim.x + threadIdx.x;
    int stride = gridDim.x * blockDim.x;
    for (; i < E; i += stride) atomicAdd(&deg[dst[i]], 1);
}

__global__ __launch_bounds__(1024) void scan_kernel(
    const int* __restrict__ deg, int* __restrict__ row_start,
    int* __restrict__ cursor, int N, int E)
{
    __shared__ int part[1024];
    int t = threadIdx.x;
    int chunk = (N + 1023) >> 10;
    int lo = t * chunk;
    int hi = min(lo + chunk, N);
    int s = 0;
    for (int i = lo; i < hi; ++i) s += deg[i];
    part[t] = s;
    __syncthreads();
    for (int off = 1; off < 1024; off <<= 1) {
        int v = (t >= off) ? part[t - off] : 0;
        __syncthreads();
        part[t] += v;
        __syncthreads();
    }
    int run = (t > 0) ? part[t - 1] : 0;
    for (int i = lo; i < hi; ++i) {
        row_start[i] = run;
        cursor[i]    = run;
        run += deg[i];
    }
    if (t == 1023) row_start[N] = E;
}

__global__ __launch_bounds__(256) void fill_kernel(
    const int* __restrict__ src, const int* __restrict__ dst,
    const float* __restrict__ ew, int* __restrict__ cursor,
    uint2* __restrict__ einfo, int E)
{
    int i = blockIdx.x * blockDim.x + threadIdx.x;
    int stride = gridDim.x * blockDim.x;
    for (; i < E; i += stride) {
        int d = dst[i];
        int pos = atomicAdd(&cursor[d], 1);
        uint2 p;
        p.x = (unsigned)src[i];
        p.y = __float_as_uint(ew[i]);
        einfo[pos] = p;
    }
}

// ===========================================================================
// Aggregation only: hout[r] = (1+eps)*x[r] + sum_j w_j * x[src_j]
// Wave-per-row, 4-way edge unroll, NO LDS, low VGPR -> full occupancy.
// 2048 blocks = 8192 waves resident => ~32K gather loads in flight.
// ===========================================================================
template<int F>
__global__ __launch_bounds__(256) void agg_kernel(
    const float* __restrict__ xin,
    const int* __restrict__ row_start,
    const uint2* __restrict__ einfo,
    const float* __restrict__ epsp,
    float* __restrict__ hout, int N)
{
    const int lane = threadIdx.x & 63;
    int w  = (blockIdx.x * 256 + threadIdx.x) >> 6;
    const int nw = (gridDim.x * 256) >> 6;
    const float eps1 = 1.0f + epsp[0];

    for (int r = w; r < N; r += nw) {
        const int rs = row_start[r];
        const int re = row_start[r + 1];

        if (F == 128) {
            float a0 = 0.f, a1 = 0.f, b0 = 0.f, b1 = 0.f;
            float c0 = 0.f, c1 = 0.f, d0 = 0.f, d1 = 0.f;
            int j = rs;
            for (; j + 4 <= re; j += 4) {
                uint2 p0 = einfo[j],     p1 = einfo[j + 1];
                uint2 p2 = einfo[j + 2], p3 = einfo[j + 3];
                float2 v0 = *reinterpret_cast<const float2*>(xin + (size_t)p0.x * 128 + lane * 2);
                float2 v1 = *reinterpret_cast<const float2*>(xin + (size_t)p1.x * 128 + lane * 2);
                float2 v2 = *reinterpret_cast<const float2*>(xin + (size_t)p2.x * 128 + lane * 2);
                float2 v3 = *reinterpret_cast<const float2*>(xin + (size_t)p3.x * 128 + lane * 2);
                float w0 = __uint_as_float(p0.y), w1 = __uint_as_float(p1.y);
                float w2 = __uint_as_float(p2.y), w3 = __uint_as_float(p3.y);
                a0 = fmaf(w0, v0.x, a0); a1 = fmaf(w0, v0.y, a1);
                b0 = fmaf(w1, v1.x, b0); b1 = fmaf(w1, v1.y, b1);
                c0 = fmaf(w2, v2.x, c0); c1 = fmaf(w2, v2.y, c1);
                d0 = fmaf(w3, v3.x, d0); d1 = fmaf(w3, v3.y, d1);
            }
            for (; j < re; ++j) {
                uint2 p = einfo[j];
                float2 v = *reinterpret_cast<const float2*>(xin + (size_t)p.x * 128 + lane * 2);
                float ww = __uint_as_float(p.y);
                a0 = fmaf(ww, v.x, a0); a1 = fmaf(ww, v.y, a1);
            }
            float2 xv = *reinterpret_cast<const float2*>(xin + (size_t)r * 128 + lane * 2);
            float2 o;
            o.x = fmaf(eps1, xv.x, (a0 + b0) + (c0 + d0));
            o.y = fmaf(eps1, xv.y, (a1 + b1) + (c1 + d1));
            *reinterpret_cast<float2*>(hout + (size_t)r * 128 + lane * 2) = o;
        } else {
            float a = 0.f, b = 0.f, c = 0.f, d = 0.f;
            int j = rs;
            for (; j + 4 <= re; j += 4) {
                uint2 p0 = einfo[j],     p1 = einfo[j + 1];
                uint2 p2 = einfo[j + 2], p3 = einfo[j + 3];
                float v0 = xin[(size_t)p0.x * 64 + lane];
                float v1 = xin[(size_t)p1.x * 64 + lane];
                float v2 = xin[(size_t)p2.x * 64 + lane];
                float v3 = xin[(size_t)p3.x * 64 + lane];
                a = fmaf(__uint_as_float(p0.y), v0, a);
                b = fmaf(__uint_as_float(p1.y), v1, b);
                c = fmaf(__uint_as_float(p2.y), v2, c);
                d = fmaf(__uint_as_float(p3.y), v3, d);
            }
            for (; j < re; ++j) {
                uint2 p = einfo[j];
                a = fmaf(__uint_as_float(p.y), xin[(size_t)p.x * 64 + lane], a);
            }
            hout[(size_t)r * 64 + lane] =
                fmaf(eps1, xin[(size_t)r * 64 + lane], (a + b) + (c + d));
        }
    }
}

// ===========================================================================
// MLP (streaming): h2 = relu(h @ Wa + ba) @ Wb + bb, accumulate BN stats
// ===========================================================================
template<int F>
__global__ __launch_bounds__(256) void mlp_kernel(
    const float* __restrict__ hbuf,
    const float* __restrict__ Wa, const float* __restrict__ ba,
    const float* __restrict__ Wb, const float* __restrict__ bb,
    float* __restrict__ h2, float* __restrict__ stats, int N)
{
    __shared__ float sWa[F * 64];
    __shared__ float sWb[64 * 64];
    __shared__ float rowbuf[4][F];
    __shared__ float red[2][4][64];

    for (int i = threadIdx.x; i < F * 64; i += 256) sWa[i] = Wa[i];
    for (int i = threadIdx.x; i < 64 * 64; i += 256) sWb[i] = Wb[i];
    __syncthreads();

    const int wid  = threadIdx.x >> 6;
    const int lane = threadIdx.x & 63;
    const float ba_l = ba[lane];
    const float bb_l = bb[lane];

    int wglobal = (blockIdx.x * 256 + threadIdx.x) >> 6;
    int nw      = (gridDim.x * 256) >> 6;

    float lsum = 0.f, lsq = 0.f;
    for (int r = wglobal; r < N; r += nw) {
        const float* hr = hbuf + (size_t)r * F;
        #pragma unroll
        for (int k = lane; k < F; k += 64) rowbuf[wid][k] = hr[k];

        float acc = ba_l;
        #pragma unroll
        for (int k = 0; k < F; k += 4) {
            float4 rv = *reinterpret_cast<const float4*>(&rowbuf[wid][k]);
            acc = fmaf(rv.x, sWa[(k + 0) * 64 + lane], acc);
            acc = fmaf(rv.y, sWa[(k + 1) * 64 + lane], acc);
            acc = fmaf(rv.z, sWa[(k + 2) * 64 + lane], acc);
            acc = fmaf(rv.w, sWa[(k + 3) * 64 + lane], acc);
        }
        acc = fmaxf(acc, 0.f);
        rowbuf[wid][lane] = acc;   // reuse first 64 floats as mid buffer

        float acc2 = bb_l;
        #pragma unroll
        for (int k = 0; k < 64; k += 4) {
            float4 mv = *reinterpret_cast<const float4*>(&rowbuf[wid][k]);
            acc2 = fmaf(mv.x, sWb[(k + 0) * 64 + lane], acc2);
            acc2 = fmaf(mv.y, sWb[(k + 1) * 64 + lane], acc2);
            acc2 = fmaf(mv.z, sWb[(k + 2) * 64 + lane], acc2);
            acc2 = fmaf(mv.w, sWb[(k + 3) * 64 + lane], acc2);
        }
        h2[(size_t)r * 64 + lane] = acc2;
        lsum += acc2;
        lsq  += acc2 * acc2;
    }

    red[0][wid][lane] = lsum;
    red[1][wid][lane] = lsq;
    __syncthreads();
    if (wid == 0) {
        float s = red[0][0][lane] + red[0][1][lane] + red[0][2][lane] + red[0][3][lane];
        float q = red[1][0][lane] + red[1][1][lane] + red[1][2][lane] + red[1][3][lane];
        atomicAdd(&stats[lane],      s);
        atomicAdd(&stats[64 + lane], q);
    }
}

// ===========================================================================
// BN finalize + apply
// ===========================================================================
__global__ void bn_finalize(const float* __restrict__ stats,
                            const float* __restrict__ g, const float* __restrict__ be,
                            float* __restrict__ ab, int N)
{
    int l = threadIdx.x;
    float invN = 1.0f / (float)N;
    float mean = stats[l] * invN;
    float var  = stats[64 + l] * invN - mean * mean;
    float a = g[l] * rsqrtf(var + BN_EPS);
    ab[l]      = a;
    ab[64 + l] = be[l] - mean * a;
}

template<int RES>
__global__ __launch_bounds__(256) void bn_apply(
    const float* __restrict__ h2, const float* __restrict__ ab,
    const float* __restrict__ res, float* __restrict__ out, int n4)
{
    int i = blockIdx.x * blockDim.x + threadIdx.x;
    int stride = gridDim.x * blockDim.x;
    for (; i < n4; i += stride) {
        float4 v = reinterpret_cast<const float4*>(h2)[i];
        int l0 = (i * 4) & 63;
        float4 o;
        o.x = fmaxf(fmaf(v.x, ab[l0 + 0], ab[64 + l0 + 0]), 0.f);
        o.y = fmaxf(fmaf(v.y, ab[l0 + 1], ab[64 + l0 + 1]), 0.f);
        o.z = fmaxf(fmaf(v.z, ab[l0 + 2], ab[64 + l0 + 2]), 0.f);
        o.w = fmaxf(fmaf(v.w, ab[l0 + 3], ab[64 + l0 + 3]), 0.f);
        if (RES) {
            float4 rv = reinterpret_cast<const float4*>(res)[i];
            o.x += rv.x; o.y += rv.y; o.z += rv.z; o.w += rv.w;
        }
        reinterpret_cast<float4*>(out)[i] = o;
    }
}

// ===========================================================================
extern "C" void kernel_launch(void* const* d_in, const int* in_sizes, int n_in,
                              void* d_out, int out_size, void* d_ws, size_t ws_size,
                              hipStream_t stream)
{
    const float* x    = (const float*)d_in[0];
    const int*   ei   = (const int*)  d_in[1];
    const float* ew   = (const float*)d_in[2];
    const float* eps1 = (const float*)d_in[3];
    const float* W1a  = (const float*)d_in[4];
    const float* b1a  = (const float*)d_in[5];
    const float* W1b  = (const float*)d_in[6];
    const float* b1b  = (const float*)d_in[7];
    const float* g1   = (const float*)d_in[8];
    const float* be1  = (const float*)d_in[9];
    const float* epss = (const float*)d_in[10];
    const float* Wsa  = (const float*)d_in[11];
    const float* bsa  = (const float*)d_in[12];
    const float* Wsb  = (const float*)d_in[13];
    const float* bsb  = (const float*)d_in[14];
    const float* gs   = (const float*)d_in[15];
    const float* bes  = (const float*)d_in[16];

    const int N   = in_sizes[0] / 128;
    const int E   = in_sizes[2];
    const int Lm1 = in_sizes[10];
    const int* src  = ei;
    const int* dstp = ei + E;

    // ---- workspace layout (overlaid; ~65 MB peak, matches proven R2 use) ----
    char* ws = (char*)d_ws;
    size_t off = 0;
    uint2* einfo = (uint2*)(ws + off);   off += (size_t)E * 8;
    float* regA  = (float*)(ws + off);   off += (size_t)N * 128 * 4;  // h1 full; later h64 | h2 halves
    int*   deg   = (int*)  (ws + off);   off += (size_t)N * 4;
    int*   row_start = (int*)(ws + off); off += (size_t)(N + 1) * 4;
    int*   cursor    = (int*)(ws + off); off += (size_t)N * 4;
    float* stats = (float*)(ws + off);   off += 128 * 4;
    float* ab    = (float*)(ws + off);
    float* outp  = (float*)d_out;
    float* bufX  = regA;                      // N*64 aggregation target (layers 2+)
    float* bufY  = regA + (size_t)N * 64;     // N*64 h2 / layer-output ping-pong

    const int n4 = N * 64 / 4;

    // ---- build CSR by dst (once per call, reused by all layers) ----
    hipMemsetAsync(deg, 0, (size_t)N * 4, stream);
    hist_kernel<<<1024, 256, 0, stream>>>(dstp, deg, E);
    scan_kernel<<<1, 1024, 0, stream>>>(deg, row_start, cursor, N, E);
    fill_kernel<<<1024, 256, 0, stream>>>(src, dstp, ew, cursor, einfo, E);

    // ---- layer 1 (F=128 -> 64) ----
    hipMemsetAsync(stats, 0, 128 * 4, stream);
    agg_kernel<128><<<2048, 256, 0, stream>>>(x, row_start, einfo, eps1, regA, N);
    mlp_kernel<128><<<2048, 256, 0, stream>>>(regA, W1a, b1a, W1b, b1b, outp, stats, N);
    bn_finalize<<<1, 64, 0, stream>>>(stats, g1, be1, ab, N);
    bn_apply<0><<<2048, 256, 0, stream>>>(outp, ab, nullptr, outp, n4);   // outp = h1bn

    // ---- layers 2..L (F=64 -> 64, residual) ----
    // i even: hin=outp, T=bufY ; i odd: hin=bufY, T=outp. bufX = agg scratch.
    float* hin = outp;
    for (int i = 0; i < Lm1; ++i) {
        float* T = (i & 1) ? outp : bufY;
        hipMemsetAsync(stats, 0, 128 * 4, stream);
        agg_kernel<64><<<2048, 256, 0, stream>>>(hin, row_start, einfo, epss + i, bufX, N);
        mlp_kernel<64><<<2048, 256, 0, stream>>>(bufX,
            Wsa + (size_t)i * 64 * 64, bsa + (size_t)i * 64,
            Wsb + (size_t)i * 64 * 64, bsb + (size_t)i * 64,
            T, stats, N);
        bn_finalize<<<1, 64, 0, stream>>>(stats, gs + (size_t)i * 64, bes + (size_t)i * 64, ab, N);
        bn_apply<1><<<2048, 256, 0, stream>>>(T, ab, hin, T, n4);   // in-place over h2
        hin = T;
    }
    if (hin != outp)   // odd Lm1: move final result into d_out
        hipMemcpyAsync(outp, hin, (size_t)N * 64 * 4, hipMemcpyDeviceToDevice, stream);
}

// Round 4
// 831.186 us; speedup vs baseline: 2.7986x; 1.2614x over previous
//
#include <hip/hip_runtime.h>

#define BN_EPS 1e-5f

// ===========================================================================
// CSR construction (by dst): histogram -> 3-phase parallel scan -> bucket fill
// ===========================================================================
__global__ __launch_bounds__(256) void hist_kernel(
    const int* __restrict__ dst, int* __restrict__ deg, int E)
{
    int i = blockIdx.x * blockDim.x + threadIdx.x;
    int stride = gridDim.x * blockDim.x;
    for (; i < E; i += stride) atomicAdd(&deg[dst[i]], 1);
}

// phase 1: per-block chunk sums (512 elems/block, int2 per thread)
__global__ __launch_bounds__(256) void scan_part1(
    const int* __restrict__ deg, int* __restrict__ blockSums, int N)
{
    __shared__ int sm[256];
    int t = threadIdx.x;
    int i0 = blockIdx.x * 512 + t * 2;
    int a = (i0     < N) ? deg[i0]     : 0;
    int b = (i0 + 1 < N) ? deg[i0 + 1] : 0;
    sm[t] = a + b;
    __syncthreads();
    for (int off = 128; off > 0; off >>= 1) {
        if (t < off) sm[t] += sm[t + off];
        __syncthreads();
    }
    if (t == 0) blockSums[blockIdx.x] = sm[0];
}

// phase 2: exclusive scan of block sums (single block)
__global__ __launch_bounds__(256) void scan_part2(
    const int* __restrict__ blockSums, int* __restrict__ blockOff, int NB)
{
    __shared__ int sm[256];
    int t = threadIdx.x;
    sm[t] = (t < NB) ? blockSums[t] : 0;
    __syncthreads();
    for (int off = 1; off < 256; off <<= 1) {
        int v = (t >= off) ? sm[t - off] : 0;
        __syncthreads();
        sm[t] += v;
        __syncthreads();
    }
    if (t < NB) blockOff[t] = (t > 0) ? sm[t - 1] : 0;
}

// phase 3: block-local exclusive prefix + global offset -> row_start, cursor
__global__ __launch_bounds__(256) void scan_part3(
    const int* __restrict__ deg, const int* __restrict__ blockOff,
    int* __restrict__ row_start, int* __restrict__ cursor, int N, int E)
{
    __shared__ int sm[256];
    int t = threadIdx.x;
    int i0 = blockIdx.x * 512 + t * 2;
    int a = (i0     < N) ? deg[i0]     : 0;
    int b = (i0 + 1 < N) ? deg[i0 + 1] : 0;
    sm[t] = a + b;
    __syncthreads();
    for (int off = 1; off < 256; off <<= 1) {
        int v = (t >= off) ? sm[t - off] : 0;
        __syncthreads();
        sm[t] += v;
        __syncthreads();
    }
    int excl = blockOff[blockIdx.x] + ((t > 0) ? sm[t - 1] : 0);
    if (i0 < N)     { row_start[i0]     = excl;     cursor[i0]     = excl; }
    if (i0 + 1 < N) { row_start[i0 + 1] = excl + a; cursor[i0 + 1] = excl + a; }
    if (blockIdx.x == 0 && t == 0) row_start[N] = E;
}

__global__ __launch_bounds__(256) void fill_kernel(
    const int* __restrict__ src, const int* __restrict__ dst,
    const float* __restrict__ ew, int* __restrict__ cursor,
    uint2* __restrict__ einfo, int E)
{
    int i = blockIdx.x * blockDim.x + threadIdx.x;
    int stride = gridDim.x * blockDim.x;
    for (; i < E; i += stride) {
        int d = dst[i];
        int pos = atomicAdd(&cursor[d], 1);
        uint2 p;
        p.x = (unsigned)src[i];
        p.y = __float_as_uint(ew[i]);
        einfo[pos] = p;
    }
}

// ===========================================================================
// Aggregation only: hout[r] = (1+eps)*x[r] + sum_j w_j * x[src_j]
// Wave-per-row, 4-way edge unroll, NO LDS, low VGPR -> full occupancy.
// ===========================================================================
template<int F>
__global__ __launch_bounds__(256) void agg_kernel(
    const float* __restrict__ xin,
    const int* __restrict__ row_start,
    const uint2* __restrict__ einfo,
    const float* __restrict__ epsp,
    float* __restrict__ hout, int N)
{
    const int lane = threadIdx.x & 63;
    int w  = (blockIdx.x * 256 + threadIdx.x) >> 6;
    const int nw = (gridDim.x * 256) >> 6;
    const float eps1 = 1.0f + epsp[0];

    for (int r = w; r < N; r += nw) {
        const int rs = row_start[r];
        const int re = row_start[r + 1];

        if (F == 128) {
            float a0 = 0.f, a1 = 0.f, b0 = 0.f, b1 = 0.f;
            float c0 = 0.f, c1 = 0.f, d0 = 0.f, d1 = 0.f;
            int j = rs;
            for (; j + 4 <= re; j += 4) {
                uint2 p0 = einfo[j],     p1 = einfo[j + 1];
                uint2 p2 = einfo[j + 2], p3 = einfo[j + 3];
                float2 v0 = *reinterpret_cast<const float2*>(xin + (size_t)p0.x * 128 + lane * 2);
                float2 v1 = *reinterpret_cast<const float2*>(xin + (size_t)p1.x * 128 + lane * 2);
                float2 v2 = *reinterpret_cast<const float2*>(xin + (size_t)p2.x * 128 + lane * 2);
                float2 v3 = *reinterpret_cast<const float2*>(xin + (size_t)p3.x * 128 + lane * 2);
                float w0 = __uint_as_float(p0.y), w1 = __uint_as_float(p1.y);
                float w2 = __uint_as_float(p2.y), w3 = __uint_as_float(p3.y);
                a0 = fmaf(w0, v0.x, a0); a1 = fmaf(w0, v0.y, a1);
                b0 = fmaf(w1, v1.x, b0); b1 = fmaf(w1, v1.y, b1);
                c0 = fmaf(w2, v2.x, c0); c1 = fmaf(w2, v2.y, c1);
                d0 = fmaf(w3, v3.x, d0); d1 = fmaf(w3, v3.y, d1);
            }
            for (; j < re; ++j) {
                uint2 p = einfo[j];
                float2 v = *reinterpret_cast<const float2*>(xin + (size_t)p.x * 128 + lane * 2);
                float ww = __uint_as_float(p.y);
                a0 = fmaf(ww, v.x, a0); a1 = fmaf(ww, v.y, a1);
            }
            float2 xv = *reinterpret_cast<const float2*>(xin + (size_t)r * 128 + lane * 2);
            float2 o;
            o.x = fmaf(eps1, xv.x, (a0 + b0) + (c0 + d0));
            o.y = fmaf(eps1, xv.y, (a1 + b1) + (c1 + d1));
            *reinterpret_cast<float2*>(hout + (size_t)r * 128 + lane * 2) = o;
        } else {
            float a = 0.f, b = 0.f, c = 0.f, d = 0.f;
            int j = rs;
            for (; j + 4 <= re; j += 4) {
                uint2 p0 = einfo[j],     p1 = einfo[j + 1];
                uint2 p2 = einfo[j + 2], p3 = einfo[j + 3];
                float v0 = xin[(size_t)p0.x * 64 + lane];
                float v1 = xin[(size_t)p1.x * 64 + lane];
                float v2 = xin[(size_t)p2.x * 64 + lane];
                float v3 = xin[(size_t)p3.x * 64 + lane];
                a = fmaf(__uint_as_float(p0.y), v0, a);
                b = fmaf(__uint_as_float(p1.y), v1, b);
                c = fmaf(__uint_as_float(p2.y), v2, c);
                d = fmaf(__uint_as_float(p3.y), v3, d);
            }
            for (; j < re; ++j) {
                uint2 p = einfo[j];
                a = fmaf(__uint_as_float(p.y), xin[(size_t)p.x * 64 + lane], a);
            }
            hout[(size_t)r * 64 + lane] =
                fmaf(eps1, xin[(size_t)r * 64 + lane], (a + b) + (c + d));
        }
    }
}

// ===========================================================================
// MLP (streaming): h2 = relu(h @ Wa + ba) @ Wb + bb, accumulate BN stats
// ===========================================================================
template<int F>
__global__ __launch_bounds__(256) void mlp_kernel(
    const float* __restrict__ hbuf,
    const float* __restrict__ Wa, const float* __restrict__ ba,
    const float* __restrict__ Wb, const float* __restrict__ bb,
    float* __restrict__ h2, float* __restrict__ stats, int N)
{
    __shared__ float sWa[F * 64];
    __shared__ float sWb[64 * 64];
    __shared__ float rowbuf[4][F];
    __shared__ float red[2][4][64];

    for (int i = threadIdx.x; i < F * 64; i += 256) sWa[i] = Wa[i];
    for (int i = threadIdx.x; i < 64 * 64; i += 256) sWb[i] = Wb[i];
    __syncthreads();

    const int wid  = threadIdx.x >> 6;
    const int lane = threadIdx.x & 63;
    const float ba_l = ba[lane];
    const float bb_l = bb[lane];

    int wglobal = (blockIdx.x * 256 + threadIdx.x) >> 6;
    int nw      = (gridDim.x * 256) >> 6;

    float lsum = 0.f, lsq = 0.f;
    for (int r = wglobal; r < N; r += nw) {
        const float* hr = hbuf + (size_t)r * F;
        #pragma unroll
        for (int k = lane; k < F; k += 64) rowbuf[wid][k] = hr[k];

        float acc = ba_l;
        #pragma unroll
        for (int k = 0; k < F; k += 4) {
            float4 rv = *reinterpret_cast<const float4*>(&rowbuf[wid][k]);
            acc = fmaf(rv.x, sWa[(k + 0) * 64 + lane], acc);
            acc = fmaf(rv.y, sWa[(k + 1) * 64 + lane], acc);
            acc = fmaf(rv.z, sWa[(k + 2) * 64 + lane], acc);
            acc = fmaf(rv.w, sWa[(k + 3) * 64 + lane], acc);
        }
        acc = fmaxf(acc, 0.f);
        rowbuf[wid][lane] = acc;   // reuse first 64 floats as mid buffer

        float acc2 = bb_l;
        #pragma unroll
        for (int k = 0; k < 64; k += 4) {
            float4 mv = *reinterpret_cast<const float4*>(&rowbuf[wid][k]);
            acc2 = fmaf(mv.x, sWb[(k + 0) * 64 + lane], acc2);
            acc2 = fmaf(mv.y, sWb[(k + 1) * 64 + lane], acc2);
            acc2 = fmaf(mv.z, sWb[(k + 2) * 64 + lane], acc2);
            acc2 = fmaf(mv.w, sWb[(k + 3) * 64 + lane], acc2);
        }
        h2[(size_t)r * 64 + lane] = acc2;
        lsum += acc2;
        lsq  += acc2 * acc2;
    }

    red[0][wid][lane] = lsum;
    red[1][wid][lane] = lsq;
    __syncthreads();
    if (wid == 0) {
        float s = red[0][0][lane] + red[0][1][lane] + red[0][2][lane] + red[0][3][lane];
        float q = red[1][0][lane] + red[1][1][lane] + red[1][2][lane] + red[1][3][lane];
        atomicAdd(&stats[lane],      s);
        atomicAdd(&stats[64 + lane], q);
    }
}

// ===========================================================================
// BN finalize + apply
// ===========================================================================
__global__ void bn_finalize(const float* __restrict__ stats,
                            const float* __restrict__ g, const float* __restrict__ be,
                            float* __restrict__ ab, int N)
{
    int l = threadIdx.x;
    float invN = 1.0f / (float)N;
    float mean = stats[l] * invN;
    float var  = stats[64 + l] * invN - mean * mean;
    float a = g[l] * rsqrtf(var + BN_EPS);
    ab[l]      = a;
    ab[64 + l] = be[l] - mean * a;
}

template<int RES>
__global__ __launch_bounds__(256) void bn_apply(
    const float* __restrict__ h2, const float* __restrict__ ab,
    const float* __restrict__ res, float* __restrict__ out, int n4)
{
    int i = blockIdx.x * blockDim.x + threadIdx.x;
    int stride = gridDim.x * blockDim.x;
    for (; i < n4; i += stride) {
        float4 v = reinterpret_cast<const float4*>(h2)[i];
        int l0 = (i * 4) & 63;
        float4 o;
        o.x = fmaxf(fmaf(v.x, ab[l0 + 0], ab[64 + l0 + 0]), 0.f);
        o.y = fmaxf(fmaf(v.y, ab[l0 + 1], ab[64 + l0 + 1]), 0.f);
        o.z = fmaxf(fmaf(v.z, ab[l0 + 2], ab[64 + l0 + 2]), 0.f);
        o.w = fmaxf(fmaf(v.w, ab[l0 + 3], ab[64 + l0 + 3]), 0.f);
        if (RES) {
            float4 rv = reinterpret_cast<const float4*>(res)[i];
            o.x += rv.x; o.y += rv.y; o.z += rv.z; o.w += rv.w;
        }
        reinterpret_cast<float4*>(out)[i] = o;
    }
}

// ===========================================================================
extern "C" void kernel_launch(void* const* d_in, const int* in_sizes, int n_in,
                              void* d_out, int out_size, void* d_ws, size_t ws_size,
                              hipStream_t stream)
{
    const float* x    = (const float*)d_in[0];
    const int*   ei   = (const int*)  d_in[1];
    const float* ew   = (const float*)d_in[2];
    const float* eps1 = (const float*)d_in[3];
    const float* W1a  = (const float*)d_in[4];
    const float* b1a  = (const float*)d_in[5];
    const float* W1b  = (const float*)d_in[6];
    const float* b1b  = (const float*)d_in[7];
    const float* g1   = (const float*)d_in[8];
    const float* be1  = (const float*)d_in[9];
    const float* epss = (const float*)d_in[10];
    const float* Wsa  = (const float*)d_in[11];
    const float* bsa  = (const float*)d_in[12];
    const float* Wsb  = (const float*)d_in[13];
    const float* bsb  = (const float*)d_in[14];
    const float* gs   = (const float*)d_in[15];
    const float* bes  = (const float*)d_in[16];

    const int N   = in_sizes[0] / 128;
    const int E   = in_sizes[2];
    const int Lm1 = in_sizes[10];
    const int* src  = ei;
    const int* dstp = ei + E;

    // ---- workspace layout ----
    char* ws = (char*)d_ws;
    size_t off = 0;
    uint2* einfo = (uint2*)(ws + off);   off += (size_t)E * 8;
    float* regA  = (float*)(ws + off);   off += (size_t)N * 128 * 4;  // h1 full; later h64 | h2 halves
    int*   deg   = (int*)  (ws + off);   off += (size_t)N * 4;
    int*   row_start = (int*)(ws + off); off += (size_t)(N + 1) * 4;
    int*   cursor    = (int*)(ws + off); off += (size_t)N * 4;
    float* stats = (float*)(ws + off);   off += 128 * 4;
    float* ab    = (float*)(ws + off);   off += 128 * 4;
    int*   blockSums = (int*)(ws + off); off += 256 * 4;
    int*   blockOff  = (int*)(ws + off);
    float* outp  = (float*)d_out;
    float* bufX  = regA;                      // N*64 aggregation target (layers 2+)
    float* bufY  = regA + (size_t)N * 64;     // N*64 h2 / layer-output ping-pong

    const int n4 = N * 64 / 4;
    const int NB = (N + 511) / 512;           // scan blocks (<=256 for N<=131072)

    // ---- build CSR by dst (once per call, reused by all layers) ----
    hipMemsetAsync(deg, 0, (size_t)N * 4, stream);
    hist_kernel<<<1024, 256, 0, stream>>>(dstp, deg, E);
    scan_part1<<<NB, 256, 0, stream>>>(deg, blockSums, N);
    scan_part2<<<1, 256, 0, stream>>>(blockSums, blockOff, NB);
    scan_part3<<<NB, 256, 0, stream>>>(deg, blockOff, row_start, cursor, N, E);
    fill_kernel<<<1024, 256, 0, stream>>>(src, dstp, ew, cursor, einfo, E);

    // ---- layer 1 (F=128 -> 64) ----
    hipMemsetAsync(stats, 0, 128 * 4, stream);
    agg_kernel<128><<<2048, 256, 0, stream>>>(x, row_start, einfo, eps1, regA, N);
    mlp_kernel<128><<<2048, 256, 0, stream>>>(regA, W1a, b1a, W1b, b1b, outp, stats, N);
    bn_finalize<<<1, 64, 0, stream>>>(stats, g1, be1, ab, N);
    bn_apply<0><<<2048, 256, 0, stream>>>(outp, ab, nullptr, outp, n4);   // outp = h1bn

    // ---- layers 2..L (F=64 -> 64, residual) ----
    float* hin = outp;
    for (int i = 0; i < Lm1; ++i) {
        float* T = (i & 1) ? outp : bufY;
        hipMemsetAsync(stats, 0, 128 * 4, stream);
        agg_kernel<64><<<2048, 256, 0, stream>>>(hin, row_start, einfo, epss + i, bufX, N);
        mlp_kernel<64><<<2048, 256, 0, stream>>>(bufX,
            Wsa + (size_t)i * 64 * 64, bsa + (size_t)i * 64,
            Wsb + (size_t)i * 64 * 64, bsb + (size_t)i * 64,
            T, stats, N);
        bn_finalize<<<1, 64, 0, stream>>>(stats, gs + (size_t)i * 64, bes + (size_t)i * 64, ab, N);
        bn_apply<1><<<2048, 256, 0, stream>>>(T, ab, hin, T, n4);   // in-place over h2
        hin = T;
    }
    if (hin != outp)   // odd Lm1: move final result into d_out
        hipMemcpyAsync(outp, hin, (size_t)N * 64 * 4, hipMemcpyDeviceToDevice, stream);
}

// Round 5
// 755.102 us; speedup vs baseline: 3.0806x; 1.1008x over previous
//
#include <hip/hip_runtime.h>

#define BN_EPS 1e-5f

// ===========================================================================
// CSR construction (by dst): histogram -> 3-phase parallel scan -> bucket fill
// ===========================================================================
__global__ __launch_bounds__(256) void hist_kernel(
    const int* __restrict__ dst, int* __restrict__ deg, int E)
{
    int i = blockIdx.x * blockDim.x + threadIdx.x;
    int stride = gridDim.x * blockDim.x;
    for (; i < E; i += stride) atomicAdd(&deg[dst[i]], 1);
}

__global__ __launch_bounds__(256) void scan_part1(
    const int* __restrict__ deg, int* __restrict__ blockSums, int N)
{
    __shared__ int sm[256];
    int t = threadIdx.x;
    int i0 = blockIdx.x * 512 + t * 2;
    int a = (i0     < N) ? deg[i0]     : 0;
    int b = (i0 + 1 < N) ? deg[i0 + 1] : 0;
    sm[t] = a + b;
    __syncthreads();
    for (int off = 128; off > 0; off >>= 1) {
        if (t < off) sm[t] += sm[t + off];
        __syncthreads();
    }
    if (t == 0) blockSums[blockIdx.x] = sm[0];
}

__global__ __launch_bounds__(256) void scan_part2(
    const int* __restrict__ blockSums, int* __restrict__ blockOff, int NB)
{
    __shared__ int sm[256];
    int t = threadIdx.x;
    sm[t] = (t < NB) ? blockSums[t] : 0;
    __syncthreads();
    for (int off = 1; off < 256; off <<= 1) {
        int v = (t >= off) ? sm[t - off] : 0;
        __syncthreads();
        sm[t] += v;
        __syncthreads();
    }
    if (t < NB) blockOff[t] = (t > 0) ? sm[t - 1] : 0;
}

__global__ __launch_bounds__(256) void scan_part3(
    const int* __restrict__ deg, const int* __restrict__ blockOff,
    int* __restrict__ row_start, int* __restrict__ cursor, int N, int E)
{
    __shared__ int sm[256];
    int t = threadIdx.x;
    int i0 = blockIdx.x * 512 + t * 2;
    int a = (i0     < N) ? deg[i0]     : 0;
    int b = (i0 + 1 < N) ? deg[i0 + 1] : 0;
    sm[t] = a + b;
    __syncthreads();
    for (int off = 1; off < 256; off <<= 1) {
        int v = (t >= off) ? sm[t - off] : 0;
        __syncthreads();
        sm[t] += v;
        __syncthreads();
    }
    int excl = blockOff[blockIdx.x] + ((t > 0) ? sm[t - 1] : 0);
    if (i0 < N)     { row_start[i0]     = excl;     cursor[i0]     = excl; }
    if (i0 + 1 < N) { row_start[i0 + 1] = excl + a; cursor[i0 + 1] = excl + a; }
    if (blockIdx.x == 0 && t == 0) row_start[N] = E;
}

__global__ __launch_bounds__(256) void fill_kernel(
    const int* __restrict__ src, const int* __restrict__ dst,
    const float* __restrict__ ew, int* __restrict__ cursor,
    uint2* __restrict__ einfo, int E)
{
    int i = blockIdx.x * blockDim.x + threadIdx.x;
    int stride = gridDim.x * blockDim.x;
    for (; i < E; i += stride) {
        int d = dst[i];
        int pos = atomicAdd(&cursor[d], 1);
        uint2 p;
        p.x = (unsigned)src[i];
        p.y = __float_as_uint(ew[i]);
        einfo[pos] = p;
    }
}

// ===========================================================================
// Register-tiled GEMM: out[N][64] = A[N][K] @ W[K][64] (+bias) (+BN stats)
// Block = 256 threads, tile = 64 rows; each thread owns a 4x4 output block.
// LDS: A-tile + W. 4xb128 A reads + 4xb128 W reads per 64 FMA.
// ===========================================================================
template<int K, bool STATS>
__global__ __launch_bounds__(256) void gemm64_kernel(
    const float* __restrict__ A, const float* __restrict__ W,
    const float* __restrict__ bias, float* __restrict__ out,
    float* __restrict__ stats, int N)
{
    __shared__ float sA[64][K];
    __shared__ float sW[K][64];
    __shared__ float ssum[64];
    __shared__ float ssq[64];

    const int tid = threadIdx.x;
    const int r0  = blockIdx.x * 64;
    constexpr int C4 = K / 4;   // float4 per row

    // stage W (K*16 float4)
    for (int i = tid; i < K * 16; i += 256)
        reinterpret_cast<float4*>(&sW[0][0])[i] =
            reinterpret_cast<const float4*>(W)[i];
    // stage A-tile (64*C4 float4), zero-pad tail rows
    for (int i = tid; i < 64 * C4; i += 256) {
        int r  = i / C4;
        int c4 = i % C4;
        float4 v = make_float4(0.f, 0.f, 0.f, 0.f);
        if (r0 + r < N)
            v = reinterpret_cast<const float4*>(A + (size_t)(r0 + r) * K)[c4];
        reinterpret_cast<float4*>(&sA[r][0])[c4] = v;
    }
    if (STATS && tid < 64) { ssum[tid] = 0.f; ssq[tid] = 0.f; }
    __syncthreads();

    const int rr = (tid >> 4) * 4;
    const int cc = (tid & 15) * 4;

    float4 bv = make_float4(0.f, 0.f, 0.f, 0.f);
    if (bias) bv = *reinterpret_cast<const float4*>(bias + cc);

    float acc[4][4];
    #pragma unroll
    for (int i = 0; i < 4; ++i) {
        acc[i][0] = bv.x; acc[i][1] = bv.y; acc[i][2] = bv.z; acc[i][3] = bv.w;
    }

    for (int k = 0; k < K; k += 4) {
        float4 w0 = *reinterpret_cast<const float4*>(&sW[k + 0][cc]);
        float4 w1 = *reinterpret_cast<const float4*>(&sW[k + 1][cc]);
        float4 w2 = *reinterpret_cast<const float4*>(&sW[k + 2][cc]);
        float4 w3 = *reinterpret_cast<const float4*>(&sW[k + 3][cc]);
        #pragma unroll
        for (int i = 0; i < 4; ++i) {
            float4 av = *reinterpret_cast<const float4*>(&sA[rr + i][k]);
            acc[i][0] = fmaf(av.x, w0.x, fmaf(av.y, w1.x, fmaf(av.z, w2.x, fmaf(av.w, w3.x, acc[i][0]))));
            acc[i][1] = fmaf(av.x, w0.y, fmaf(av.y, w1.y, fmaf(av.z, w2.y, fmaf(av.w, w3.y, acc[i][1]))));
            acc[i][2] = fmaf(av.x, w0.z, fmaf(av.y, w1.z, fmaf(av.z, w2.z, fmaf(av.w, w3.z, acc[i][2]))));
            acc[i][3] = fmaf(av.x, w0.w, fmaf(av.y, w1.w, fmaf(av.z, w2.w, fmaf(av.w, w3.w, acc[i][3]))));
        }
    }

    // store
    #pragma unroll
    for (int i = 0; i < 4; ++i) {
        int r = r0 + rr + i;
        if (r < N) {
            float4 o = make_float4(acc[i][0], acc[i][1], acc[i][2], acc[i][3]);
            *reinterpret_cast<float4*>(out + (size_t)r * 64 + cc) = o;
        }
    }

    if (STATS) {
        #pragma unroll
        for (int j = 0; j < 4; ++j) {
            float s = 0.f, q = 0.f;
            #pragma unroll
            for (int i = 0; i < 4; ++i) {
                if (r0 + rr + i < N) {
                    float v = acc[i][j];
                    s += v; q += v * v;
                }
            }
            atomicAdd(&ssum[cc + j], s);
            atomicAdd(&ssq[cc + j], q);
        }
        __syncthreads();
        if (tid < 64) {
            atomicAdd(&stats[tid],      ssum[tid]);
            atomicAdd(&stats[64 + tid], ssq[tid]);
        }
    }
}

// ===========================================================================
// Gather-aggregate in 64-dim + bias + relu:
//   mid[r] = relu((1+eps)*y[r] + sum_j w_j * y[src_j] + ba)
// Wave-per-row, 4-way edge unroll, no LDS -> full occupancy.
// ===========================================================================
__global__ __launch_bounds__(256) void aggmid_kernel(
    const float* __restrict__ y,
    const int* __restrict__ row_start,
    const uint2* __restrict__ einfo,
    const float* __restrict__ epsp,
    const float* __restrict__ ba,
    float* __restrict__ mid, int N)
{
    const int lane = threadIdx.x & 63;
    int w  = (blockIdx.x * 256 + threadIdx.x) >> 6;
    const int nw = (gridDim.x * 256) >> 6;
    const float eps1 = 1.0f + epsp[0];
    const float ba_l = ba[lane];

    for (int r = w; r < N; r += nw) {
        const int rs = row_start[r];
        const int re = row_start[r + 1];

        float a = 0.f, b = 0.f, c = 0.f, d = 0.f;
        int j = rs;
        for (; j + 4 <= re; j += 4) {
            uint2 p0 = einfo[j],     p1 = einfo[j + 1];
            uint2 p2 = einfo[j + 2], p3 = einfo[j + 3];
            float v0 = y[(size_t)p0.x * 64 + lane];
            float v1 = y[(size_t)p1.x * 64 + lane];
            float v2 = y[(size_t)p2.x * 64 + lane];
            float v3 = y[(size_t)p3.x * 64 + lane];
            a = fmaf(__uint_as_float(p0.y), v0, a);
            b = fmaf(__uint_as_float(p1.y), v1, b);
            c = fmaf(__uint_as_float(p2.y), v2, c);
            d = fmaf(__uint_as_float(p3.y), v3, d);
        }
        for (; j < re; ++j) {
            uint2 p = einfo[j];
            a = fmaf(__uint_as_float(p.y), y[(size_t)p.x * 64 + lane], a);
        }
        float v = fmaf(eps1, y[(size_t)r * 64 + lane], (a + b) + (c + d)) + ba_l;
        mid[(size_t)r * 64 + lane] = fmaxf(v, 0.f);
    }
}

// ===========================================================================
// BN finalize + apply
// ===========================================================================
__global__ void bn_finalize(const float* __restrict__ stats,
                            const float* __restrict__ g, const float* __restrict__ be,
                            float* __restrict__ ab, int N)
{
    int l = threadIdx.x;
    float invN = 1.0f / (float)N;
    float mean = stats[l] * invN;
    float var  = stats[64 + l] * invN - mean * mean;
    float a = g[l] * rsqrtf(var + BN_EPS);
    ab[l]      = a;
    ab[64 + l] = be[l] - mean * a;
}

template<int RES>
__global__ __launch_bounds__(256) void bn_apply(
    const float* __restrict__ h2, const float* __restrict__ ab,
    const float* res, float* out, int n4)   // res/out may alias (in-place)
{
    int i = blockIdx.x * blockDim.x + threadIdx.x;
    int stride = gridDim.x * blockDim.x;
    for (; i < n4; i += stride) {
        float4 v = reinterpret_cast<const float4*>(h2)[i];
        int l0 = (i * 4) & 63;
        float4 o;
        o.x = fmaxf(fmaf(v.x, ab[l0 + 0], ab[64 + l0 + 0]), 0.f);
        o.y = fmaxf(fmaf(v.y, ab[l0 + 1], ab[64 + l0 + 1]), 0.f);
        o.z = fmaxf(fmaf(v.z, ab[l0 + 2], ab[64 + l0 + 2]), 0.f);
        o.w = fmaxf(fmaf(v.w, ab[l0 + 3], ab[64 + l0 + 3]), 0.f);
        if (RES) {
            float4 rv = reinterpret_cast<const float4*>(res)[i];
            o.x += rv.x; o.y += rv.y; o.z += rv.z; o.w += rv.w;
        }
        reinterpret_cast<float4*>(out)[i] = o;
    }
}

// ===========================================================================
extern "C" void kernel_launch(void* const* d_in, const int* in_sizes, int n_in,
                              void* d_out, int out_size, void* d_ws, size_t ws_size,
                              hipStream_t stream)
{
    const float* x    = (const float*)d_in[0];
    const int*   ei   = (const int*)  d_in[1];
    const float* ew   = (const float*)d_in[2];
    const float* eps1 = (const float*)d_in[3];
    const float* W1a  = (const float*)d_in[4];
    const float* b1a  = (const float*)d_in[5];
    const float* W1b  = (const float*)d_in[6];
    const float* b1b  = (const float*)d_in[7];
    const float* g1   = (const float*)d_in[8];
    const float* be1  = (const float*)d_in[9];
    const float* epss = (const float*)d_in[10];
    const float* Wsa  = (const float*)d_in[11];
    const float* bsa  = (const float*)d_in[12];
    const float* Wsb  = (const float*)d_in[13];
    const float* bsb  = (const float*)d_in[14];
    const float* gs   = (const float*)d_in[15];
    const float* bes  = (const float*)d_in[16];

    const int N   = in_sizes[0] / 128;
    const int E   = in_sizes[2];
    const int Lm1 = in_sizes[10];
    const int* src  = ei;
    const int* dstp = ei + E;

    // ---- workspace layout ----
    char* ws = (char*)d_ws;
    size_t off = 0;
    uint2* einfo = (uint2*)(ws + off);   off += (size_t)E * 8;
    float* regA  = (float*)(ws + off);   off += (size_t)N * 128 * 4;  // bufX | bufY
    int*   deg   = (int*)  (ws + off);   off += (size_t)N * 4;
    int*   row_start = (int*)(ws + off); off += (size_t)(N + 1) * 4;
    int*   cursor    = (int*)(ws + off); off += (size_t)N * 4;
    float* stats = (float*)(ws + off);   off += 128 * 4;
    float* ab    = (float*)(ws + off);   off += 128 * 4;
    int*   blockSums = (int*)(ws + off); off += 256 * 4;
    int*   blockOff  = (int*)(ws + off);
    float* outp  = (float*)d_out;
    float* bufX  = regA;                      // y / h2 scratch (N*64)
    float* bufY  = regA + (size_t)N * 64;     // mid scratch (N*64)

    const int n4   = N * 64 / 4;
    const int NB   = (N + 511) / 512;         // scan blocks
    const int NBLK = (N + 63) / 64;           // gemm row-tiles

    // ---- build CSR by dst (once per call, reused by all layers) ----
    hipMemsetAsync(deg, 0, (size_t)N * 4, stream);
    hist_kernel<<<1024, 256, 0, stream>>>(dstp, deg, E);
    scan_part1<<<NB, 256, 0, stream>>>(deg, blockSums, N);
    scan_part2<<<1, 256, 0, stream>>>(blockSums, blockOff, NB);
    scan_part3<<<NB, 256, 0, stream>>>(deg, blockOff, row_start, cursor, N, E);
    fill_kernel<<<1024, 256, 0, stream>>>(src, dstp, ew, cursor, einfo, E);

    // ---- layer 1 (F=128 -> 64): y = x@W1a first (linearity), gather in 64-dim
    gemm64_kernel<128, false><<<NBLK, 256, 0, stream>>>(x, W1a, nullptr, bufX, nullptr, N);
    aggmid_kernel<<<2048, 256, 0, stream>>>(bufX, row_start, einfo, eps1, b1a, bufY, N);
    hipMemsetAsync(stats, 0, 128 * 4, stream);
    gemm64_kernel<64, true><<<NBLK, 256, 0, stream>>>(bufY, W1b, b1b, bufX, stats, N);
    bn_finalize<<<1, 64, 0, stream>>>(stats, g1, be1, ab, N);
    bn_apply<0><<<2048, 256, 0, stream>>>(bufX, ab, nullptr, outp, n4);

    // ---- layers 2..L (64 -> 64, residual, in-place over outp) ----
    for (int i = 0; i < Lm1; ++i) {
        gemm64_kernel<64, false><<<NBLK, 256, 0, stream>>>(
            outp, Wsa + (size_t)i * 64 * 64, nullptr, bufX, nullptr, N);
        aggmid_kernel<<<2048, 256, 0, stream>>>(
            bufX, row_start, einfo, epss + i, bsa + (size_t)i * 64, bufY, N);
        hipMemsetAsync(stats, 0, 128 * 4, stream);
        gemm64_kernel<64, true><<<NBLK, 256, 0, stream>>>(
            bufY, Wsb + (size_t)i * 64 * 64, bsb + (size_t)i * 64, bufX, stats, N);
        bn_finalize<<<1, 64, 0, stream>>>(stats, gs + (size_t)i * 64, bes + (size_t)i * 64, ab, N);
        bn_apply<1><<<2048, 256, 0, stream>>>(bufX, ab, outp, outp, n4);  // in-place residual
    }
}

// Round 6
// 668.118 us; speedup vs baseline: 3.4817x; 1.1302x over previous
//
#include <hip/hip_runtime.h>

#define BN_EPS 1e-5f

// ===========================================================================
// CSR construction (by dst):
//   rank pass (atomic, gives per-edge in-bucket rank + histogram)
//   -> 3-phase parallel scan -> atomic-free scatter fill
// ===========================================================================
__global__ __launch_bounds__(256) void rank_kernel(
    const int* __restrict__ dst, int* __restrict__ deg,
    int* __restrict__ rank, int E)
{
    int i = blockIdx.x * 256 + threadIdx.x;
    if (i < E) rank[i] = atomicAdd(&deg[dst[i]], 1);
}

__global__ __launch_bounds__(256) void scan_part1(
    const int* __restrict__ deg, int* __restrict__ blockSums, int N)
{
    __shared__ int sm[256];
    int t = threadIdx.x;
    int i0 = blockIdx.x * 512 + t * 2;
    int a = (i0     < N) ? deg[i0]     : 0;
    int b = (i0 + 1 < N) ? deg[i0 + 1] : 0;
    sm[t] = a + b;
    __syncthreads();
    for (int off = 128; off > 0; off >>= 1) {
        if (t < off) sm[t] += sm[t + off];
        __syncthreads();
    }
    if (t == 0) blockSums[blockIdx.x] = sm[0];
}

__global__ __launch_bounds__(256) void scan_part2(
    const int* __restrict__ blockSums, int* __restrict__ blockOff, int NB)
{
    __shared__ int sm[256];
    int t = threadIdx.x;
    sm[t] = (t < NB) ? blockSums[t] : 0;
    __syncthreads();
    for (int off = 1; off < 256; off <<= 1) {
        int v = (t >= off) ? sm[t - off] : 0;
        __syncthreads();
        sm[t] += v;
        __syncthreads();
    }
    if (t < NB) blockOff[t] = (t > 0) ? sm[t - 1] : 0;
}

__global__ __launch_bounds__(256) void scan_part3(
    const int* __restrict__ deg, const int* __restrict__ blockOff,
    int* __restrict__ row_start, int N, int E)
{
    __shared__ int sm[256];
    int t = threadIdx.x;
    int i0 = blockIdx.x * 512 + t * 2;
    int a = (i0     < N) ? deg[i0]     : 0;
    int b = (i0 + 1 < N) ? deg[i0 + 1] : 0;
    sm[t] = a + b;
    __syncthreads();
    for (int off = 1; off < 256; off <<= 1) {
        int v = (t >= off) ? sm[t - off] : 0;
        __syncthreads();
        sm[t] += v;
        __syncthreads();
    }
    int excl = blockOff[blockIdx.x] + ((t > 0) ? sm[t - 1] : 0);
    if (i0 < N)     row_start[i0]     = excl;
    if (i0 + 1 < N) row_start[i0 + 1] = excl + a;
    if (blockIdx.x == 0 && t == 0) row_start[N] = E;
}

// atomic-free fill: pos fully determined by row_start + precomputed rank
__global__ __launch_bounds__(256) void fill_pass2(
    const int* __restrict__ src, const int* __restrict__ dst,
    const float* __restrict__ ew, const int* __restrict__ rank,
    const int* __restrict__ row_start, uint2* __restrict__ einfo, int E)
{
    int i = blockIdx.x * 256 + threadIdx.x;
    if (i < E) {
        int pos = row_start[dst[i]] + rank[i];
        uint2 p;
        p.x = (unsigned)src[i];
        p.y = __float_as_uint(ew[i]);
        einfo[pos] = p;
    }
}

// ===========================================================================
// Register-tiled GEMM: out[N][64] = A[N][K] @ W[K][64] (+bias) (+BN stats)
// ===========================================================================
template<int K, bool STATS>
__global__ __launch_bounds__(256) void gemm64_kernel(
    const float* __restrict__ A, const float* __restrict__ W,
    const float* __restrict__ bias, float* __restrict__ out,
    float* __restrict__ stats, int N)
{
    __shared__ float sA[64][K];
    __shared__ float sW[K][64];
    __shared__ float ssum[64];
    __shared__ float ssq[64];

    const int tid = threadIdx.x;
    const int r0  = blockIdx.x * 64;
    constexpr int C4 = K / 4;

    for (int i = tid; i < K * 16; i += 256)
        reinterpret_cast<float4*>(&sW[0][0])[i] =
            reinterpret_cast<const float4*>(W)[i];
    for (int i = tid; i < 64 * C4; i += 256) {
        int r  = i / C4;
        int c4 = i % C4;
        float4 v = make_float4(0.f, 0.f, 0.f, 0.f);
        if (r0 + r < N)
            v = reinterpret_cast<const float4*>(A + (size_t)(r0 + r) * K)[c4];
        reinterpret_cast<float4*>(&sA[r][0])[c4] = v;
    }
    if (STATS && tid < 64) { ssum[tid] = 0.f; ssq[tid] = 0.f; }
    __syncthreads();

    const int rr = (tid >> 4) * 4;
    const int cc = (tid & 15) * 4;

    float4 bv = make_float4(0.f, 0.f, 0.f, 0.f);
    if (bias) bv = *reinterpret_cast<const float4*>(bias + cc);

    float acc[4][4];
    #pragma unroll
    for (int i = 0; i < 4; ++i) {
        acc[i][0] = bv.x; acc[i][1] = bv.y; acc[i][2] = bv.z; acc[i][3] = bv.w;
    }

    for (int k = 0; k < K; k += 4) {
        float4 w0 = *reinterpret_cast<const float4*>(&sW[k + 0][cc]);
        float4 w1 = *reinterpret_cast<const float4*>(&sW[k + 1][cc]);
        float4 w2 = *reinterpret_cast<const float4*>(&sW[k + 2][cc]);
        float4 w3 = *reinterpret_cast<const float4*>(&sW[k + 3][cc]);
        #pragma unroll
        for (int i = 0; i < 4; ++i) {
            float4 av = *reinterpret_cast<const float4*>(&sA[rr + i][k]);
            acc[i][0] = fmaf(av.x, w0.x, fmaf(av.y, w1.x, fmaf(av.z, w2.x, fmaf(av.w, w3.x, acc[i][0]))));
            acc[i][1] = fmaf(av.x, w0.y, fmaf(av.y, w1.y, fmaf(av.z, w2.y, fmaf(av.w, w3.y, acc[i][1]))));
            acc[i][2] = fmaf(av.x, w0.z, fmaf(av.y, w1.z, fmaf(av.z, w2.z, fmaf(av.w, w3.z, acc[i][2]))));
            acc[i][3] = fmaf(av.x, w0.w, fmaf(av.y, w1.w, fmaf(av.z, w2.w, fmaf(av.w, w3.w, acc[i][3]))));
        }
    }

    #pragma unroll
    for (int i = 0; i < 4; ++i) {
        int r = r0 + rr + i;
        if (r < N) {
            float4 o = make_float4(acc[i][0], acc[i][1], acc[i][2], acc[i][3]);
            *reinterpret_cast<float4*>(out + (size_t)r * 64 + cc) = o;
        }
    }

    if (STATS) {
        #pragma unroll
        for (int j = 0; j < 4; ++j) {
            float s = 0.f, q = 0.f;
            #pragma unroll
            for (int i = 0; i < 4; ++i) {
                if (r0 + rr + i < N) {
                    float v = acc[i][j];
                    s += v; q += v * v;
                }
            }
            atomicAdd(&ssum[cc + j], s);
            atomicAdd(&ssq[cc + j], q);
        }
        __syncthreads();
        if (tid < 64) {
            atomicAdd(&stats[tid],      ssum[tid]);
            atomicAdd(&stats[64 + tid], ssq[tid]);
        }
    }
}

// ===========================================================================
// Gather-aggregate in 64-dim + bias + relu:
//   mid[r] = relu((1+eps)*y[r] + sum_j w_j * y[src_j] + ba)
// ===========================================================================
__global__ __launch_bounds__(256) void aggmid_kernel(
    const float* __restrict__ y,
    const int* __restrict__ row_start,
    const uint2* __restrict__ einfo,
    const float* __restrict__ epsp,
    const float* __restrict__ ba,
    float* __restrict__ mid, int N)
{
    const int lane = threadIdx.x & 63;
    int w  = (blockIdx.x * 256 + threadIdx.x) >> 6;
    const int nw = (gridDim.x * 256) >> 6;
    const float eps1 = 1.0f + epsp[0];
    const float ba_l = ba[lane];

    for (int r = w; r < N; r += nw) {
        const int rs = row_start[r];
        const int re = row_start[r + 1];

        float a = 0.f, b = 0.f, c = 0.f, d = 0.f;
        int j = rs;
        for (; j + 4 <= re; j += 4) {
            uint2 p0 = einfo[j],     p1 = einfo[j + 1];
            uint2 p2 = einfo[j + 2], p3 = einfo[j + 3];
            float v0 = y[(size_t)p0.x * 64 + lane];
            float v1 = y[(size_t)p1.x * 64 + lane];
            float v2 = y[(size_t)p2.x * 64 + lane];
            float v3 = y[(size_t)p3.x * 64 + lane];
            a = fmaf(__uint_as_float(p0.y), v0, a);
            b = fmaf(__uint_as_float(p1.y), v1, b);
            c = fmaf(__uint_as_float(p2.y), v2, c);
            d = fmaf(__uint_as_float(p3.y), v3, d);
        }
        for (; j < re; ++j) {
            uint2 p = einfo[j];
            a = fmaf(__uint_as_float(p.y), y[(size_t)p.x * 64 + lane], a);
        }
        float v = fmaf(eps1, y[(size_t)r * 64 + lane], (a + b) + (c + d)) + ba_l;
        mid[(size_t)r * 64 + lane] = fmaxf(v, 0.f);
    }
}

// ===========================================================================
// BN finalize + apply
// ===========================================================================
__global__ void bn_finalize(const float* __restrict__ stats,
                            const float* __restrict__ g, const float* __restrict__ be,
                            float* __restrict__ ab, int N)
{
    int l = threadIdx.x;
    float invN = 1.0f / (float)N;
    float mean = stats[l] * invN;
    float var  = stats[64 + l] * invN - mean * mean;
    float a = g[l] * rsqrtf(var + BN_EPS);
    ab[l]      = a;
    ab[64 + l] = be[l] - mean * a;
}

template<int RES>
__global__ __launch_bounds__(256) void bn_apply(
    const float* __restrict__ h2, const float* __restrict__ ab,
    const float* res, float* out, int n4)   // res/out may alias (in-place)
{
    int i = blockIdx.x * blockDim.x + threadIdx.x;
    int stride = gridDim.x * blockDim.x;
    for (; i < n4; i += stride) {
        float4 v = reinterpret_cast<const float4*>(h2)[i];
        int l0 = (i * 4) & 63;
        float4 o;
        o.x = fmaxf(fmaf(v.x, ab[l0 + 0], ab[64 + l0 + 0]), 0.f);
        o.y = fmaxf(fmaf(v.y, ab[l0 + 1], ab[64 + l0 + 1]), 0.f);
        o.z = fmaxf(fmaf(v.z, ab[l0 + 2], ab[64 + l0 + 2]), 0.f);
        o.w = fmaxf(fmaf(v.w, ab[l0 + 3], ab[64 + l0 + 3]), 0.f);
        if (RES) {
            float4 rv = reinterpret_cast<const float4*>(res)[i];
            o.x += rv.x; o.y += rv.y; o.z += rv.z; o.w += rv.w;
        }
        reinterpret_cast<float4*>(out)[i] = o;
    }
}

// ===========================================================================
extern "C" void kernel_launch(void* const* d_in, const int* in_sizes, int n_in,
                              void* d_out, int out_size, void* d_ws, size_t ws_size,
                              hipStream_t stream)
{
    const float* x    = (const float*)d_in[0];
    const int*   ei   = (const int*)  d_in[1];
    const float* ew   = (const float*)d_in[2];
    const float* eps1 = (const float*)d_in[3];
    const float* W1a  = (const float*)d_in[4];
    const float* b1a  = (const float*)d_in[5];
    const float* W1b  = (const float*)d_in[6];
    const float* b1b  = (const float*)d_in[7];
    const float* g1   = (const float*)d_in[8];
    const float* be1  = (const float*)d_in[9];
    const float* epss = (const float*)d_in[10];
    const float* Wsa  = (const float*)d_in[11];
    const float* bsa  = (const float*)d_in[12];
    const float* Wsb  = (const float*)d_in[13];
    const float* bsb  = (const float*)d_in[14];
    const float* gs   = (const float*)d_in[15];
    const float* bes  = (const float*)d_in[16];

    const int N   = in_sizes[0] / 128;
    const int E   = in_sizes[2];
    const int Lm1 = in_sizes[10];
    const int* src  = ei;
    const int* dstp = ei + E;

    // ---- workspace layout ----
    char* ws = (char*)d_ws;
    size_t off = 0;
    uint2* einfo = (uint2*)(ws + off);   off += (size_t)E * 8;
    float* regA  = (float*)(ws + off);   off += (size_t)N * 128 * 4;  // bufX | bufY
    int*   rank  = (int*)  (ws + off);   off += (size_t)E * 4;
    int*   deg   = (int*)  (ws + off);   off += (size_t)N * 4;
    int*   row_start = (int*)(ws + off); off += (size_t)(N + 1) * 4;
    float* stats = (float*)(ws + off);   off += 128 * 4;
    float* ab    = (float*)(ws + off);   off += 128 * 4;
    int*   blockSums = (int*)(ws + off); off += 256 * 4;
    int*   blockOff  = (int*)(ws + off);
    float* outp  = (float*)d_out;
    float* bufX  = regA;                      // y / h2 scratch (N*64)
    float* bufY  = regA + (size_t)N * 64;     // mid scratch (N*64)

    const int n4   = N * 64 / 4;
    const int NB   = (N + 511) / 512;         // scan blocks
    const int NBLK = (N + 63) / 64;           // gemm row-tiles
    const int EB   = (E + 255) / 256;         // edge blocks (1 edge/thread)

    // ---- build CSR by dst (once per call, reused by all layers) ----
    hipMemsetAsync(deg, 0, (size_t)N * 4, stream);
    rank_kernel<<<EB, 256, 0, stream>>>(dstp, deg, rank, E);
    scan_part1<<<NB, 256, 0, stream>>>(deg, blockSums, N);
    scan_part2<<<1, 256, 0, stream>>>(blockSums, blockOff, NB);
    scan_part3<<<NB, 256, 0, stream>>>(deg, blockOff, row_start, N, E);
    fill_pass2<<<EB, 256, 0, stream>>>(src, dstp, ew, rank, row_start, einfo, E);

    // ---- layer 1 (F=128 -> 64): y = x@W1a first (linearity), gather in 64-dim
    gemm64_kernel<128, false><<<NBLK, 256, 0, stream>>>(x, W1a, nullptr, bufX, nullptr, N);
    aggmid_kernel<<<2048, 256, 0, stream>>>(bufX, row_start, einfo, eps1, b1a, bufY, N);
    hipMemsetAsync(stats, 0, 128 * 4, stream);
    gemm64_kernel<64, true><<<NBLK, 256, 0, stream>>>(bufY, W1b, b1b, bufX, stats, N);
    bn_finalize<<<1, 64, 0, stream>>>(stats, g1, be1, ab, N);
    bn_apply<0><<<2048, 256, 0, stream>>>(bufX, ab, nullptr, outp, n4);

    // ---- layers 2..L (64 -> 64, residual, in-place over outp) ----
    for (int i = 0; i < Lm1; ++i) {
        gemm64_kernel<64, false><<<NBLK, 256, 0, stream>>>(
            outp, Wsa + (size_t)i * 64 * 64, nullptr, bufX, nullptr, N);
        aggmid_kernel<<<2048, 256, 0, stream>>>(
            bufX, row_start, einfo, epss + i, bsa + (size_t)i * 64, bufY, N);
        hipMemsetAsync(stats, 0, 128 * 4, stream);
        gemm64_kernel<64, true><<<NBLK, 256, 0, stream>>>(
            bufY, Wsb + (size_t)i * 64 * 64, bsb + (size_t)i * 64, bufX, stats, N);
        bn_finalize<<<1, 64, 0, stream>>>(stats, gs + (size_t)i * 64, bes + (size_t)i * 64, ab, N);
        bn_apply<1><<<2048, 256, 0, stream>>>(bufX, ab, outp, outp, n4);  // in-place residual
    }
}

// Round 7
// 637.344 us; speedup vs baseline: 3.6498x; 1.0483x over previous
//
#include <hip/hip_runtime.h>

#define BN_EPS 1e-5f

// ===========================================================================
// CSR construction (by dst):
//   rank pass (atomic, gives per-edge in-bucket rank + histogram)
//   -> 3-phase parallel scan -> atomic-free scatter fill
// ===========================================================================
__global__ __launch_bounds__(256) void rank_kernel(
    const int* __restrict__ dst, int* __restrict__ deg,
    int* __restrict__ rank, int E)
{
    int i = blockIdx.x * 256 + threadIdx.x;
    if (i < E) rank[i] = atomicAdd(&deg[dst[i]], 1);
}

__global__ __launch_bounds__(256) void scan_part1(
    const int* __restrict__ deg, int* __restrict__ blockSums, int N)
{
    __shared__ int sm[256];
    int t = threadIdx.x;
    int i0 = blockIdx.x * 512 + t * 2;
    int a = (i0     < N) ? deg[i0]     : 0;
    int b = (i0 + 1 < N) ? deg[i0 + 1] : 0;
    sm[t] = a + b;
    __syncthreads();
    for (int off = 128; off > 0; off >>= 1) {
        if (t < off) sm[t] += sm[t + off];
        __syncthreads();
    }
    if (t == 0) blockSums[blockIdx.x] = sm[0];
}

__global__ __launch_bounds__(256) void scan_part2(
    const int* __restrict__ blockSums, int* __restrict__ blockOff, int NB)
{
    __shared__ int sm[256];
    int t = threadIdx.x;
    sm[t] = (t < NB) ? blockSums[t] : 0;
    __syncthreads();
    for (int off = 1; off < 256; off <<= 1) {
        int v = (t >= off) ? sm[t - off] : 0;
        __syncthreads();
        sm[t] += v;
        __syncthreads();
    }
    if (t < NB) blockOff[t] = (t > 0) ? sm[t - 1] : 0;
}

__global__ __launch_bounds__(256) void scan_part3(
    const int* __restrict__ deg, const int* __restrict__ blockOff,
    int* __restrict__ row_start, int N, int E)
{
    __shared__ int sm[256];
    int t = threadIdx.x;
    int i0 = blockIdx.x * 512 + t * 2;
    int a = (i0     < N) ? deg[i0]     : 0;
    int b = (i0 + 1 < N) ? deg[i0 + 1] : 0;
    sm[t] = a + b;
    __syncthreads();
    for (int off = 1; off < 256; off <<= 1) {
        int v = (t >= off) ? sm[t - off] : 0;
        __syncthreads();
        sm[t] += v;
        __syncthreads();
    }
    int excl = blockOff[blockIdx.x] + ((t > 0) ? sm[t - 1] : 0);
    if (i0 < N)     row_start[i0]     = excl;
    if (i0 + 1 < N) row_start[i0 + 1] = excl + a;
    if (blockIdx.x == 0 && t == 0) row_start[N] = E;
}

__global__ __launch_bounds__(256) void fill_pass2(
    const int* __restrict__ src, const int* __restrict__ dst,
    const float* __restrict__ ew, const int* __restrict__ rank,
    const int* __restrict__ row_start, uint2* __restrict__ einfo, int E)
{
    int i = blockIdx.x * 256 + threadIdx.x;
    if (i < E) {
        int pos = row_start[dst[i]] + rank[i];
        uint2 p;
        p.x = (unsigned)src[i];
        p.y = __float_as_uint(ew[i]);
        einfo[pos] = p;
    }
}

// ===========================================================================
// Register-tiled GEMM: out[N][64] = A[N][K] @ W[K][64] (+bias) (+BN stats)
// 256 thr, 64-row tile, 4x4 per thread. launch_bounds caps VGPR at 128.
// Stats reduction: conflict-free tree reduce aliased onto sA (no LDS atomics).
// ===========================================================================
template<int K, bool STATS>
__global__ __launch_bounds__(256, 4) void gemm64_kernel(
    const float* __restrict__ A, const float* __restrict__ W,
    const float* __restrict__ bias, float* __restrict__ out,
    float* __restrict__ stats, int N)
{
    __shared__ float sA[64][K];
    __shared__ float sW[K][64];

    const int tid = threadIdx.x;
    const int r0  = blockIdx.x * 64;
    constexpr int C4 = K / 4;

    for (int i = tid; i < K * 16; i += 256)
        reinterpret_cast<float4*>(&sW[0][0])[i] =
            reinterpret_cast<const float4*>(W)[i];
    for (int i = tid; i < 64 * C4; i += 256) {
        int r  = i / C4;
        int c4 = i % C4;
        float4 v = make_float4(0.f, 0.f, 0.f, 0.f);
        if (r0 + r < N)
            v = reinterpret_cast<const float4*>(A + (size_t)(r0 + r) * K)[c4];
        reinterpret_cast<float4*>(&sA[r][0])[c4] = v;
    }
    __syncthreads();

    const int rr = (tid >> 4) * 4;
    const int cc = (tid & 15) * 4;

    float4 bv = make_float4(0.f, 0.f, 0.f, 0.f);
    if (bias) bv = *reinterpret_cast<const float4*>(bias + cc);

    float acc[4][4];
    #pragma unroll
    for (int i = 0; i < 4; ++i) {
        acc[i][0] = bv.x; acc[i][1] = bv.y; acc[i][2] = bv.z; acc[i][3] = bv.w;
    }

    #pragma unroll 4
    for (int k = 0; k < K; k += 4) {
        float4 w0 = *reinterpret_cast<const float4*>(&sW[k + 0][cc]);
        float4 w1 = *reinterpret_cast<const float4*>(&sW[k + 1][cc]);
        float4 w2 = *reinterpret_cast<const float4*>(&sW[k + 2][cc]);
        float4 w3 = *reinterpret_cast<const float4*>(&sW[k + 3][cc]);
        #pragma unroll
        for (int i = 0; i < 4; ++i) {
            float4 av = *reinterpret_cast<const float4*>(&sA[rr + i][k]);
            acc[i][0] = fmaf(av.x, w0.x, fmaf(av.y, w1.x, fmaf(av.z, w2.x, fmaf(av.w, w3.x, acc[i][0]))));
            acc[i][1] = fmaf(av.x, w0.y, fmaf(av.y, w1.y, fmaf(av.z, w2.y, fmaf(av.w, w3.y, acc[i][1]))));
            acc[i][2] = fmaf(av.x, w0.z, fmaf(av.y, w1.z, fmaf(av.z, w2.z, fmaf(av.w, w3.z, acc[i][2]))));
            acc[i][3] = fmaf(av.x, w0.w, fmaf(av.y, w1.w, fmaf(av.z, w2.w, fmaf(av.w, w3.w, acc[i][3]))));
        }
    }

    #pragma unroll
    for (int i = 0; i < 4; ++i) {
        int r = r0 + rr + i;
        if (r < N) {
            float4 o = make_float4(acc[i][0], acc[i][1], acc[i][2], acc[i][3]);
            *reinterpret_cast<float4*>(out + (size_t)r * 64 + cc) = o;
        }
    }

    if (STATS) {
        // per-thread column partials over its 4 rows (masking pad rows)
        float cs[4], cq[4];
        #pragma unroll
        for (int j = 0; j < 4; ++j) {
            cs[j] = 0.f; cq[j] = 0.f;
            #pragma unroll
            for (int i = 0; i < 4; ++i) {
                if (r0 + rr + i < N) {
                    float v = acc[i][j];
                    cs[j] += v; cq[j] += v * v;
                }
            }
        }
        __syncthreads();                 // done reading sA; reuse as reduce buf
        float* red = &sA[0][0];          // [16][64]
        const int g = tid >> 4;
        #pragma unroll
        for (int j = 0; j < 4; ++j) red[g * 64 + cc + j] = cs[j];
        __syncthreads();
        if (tid < 64) {
            float s = 0.f;
            #pragma unroll
            for (int g2 = 0; g2 < 16; ++g2) s += red[g2 * 64 + tid];
            atomicAdd(&stats[tid], s);
        }
        __syncthreads();
        #pragma unroll
        for (int j = 0; j < 4; ++j) red[g * 64 + cc + j] = cq[j];
        __syncthreads();
        if (tid < 64) {
            float q = 0.f;
            #pragma unroll
            for (int g2 = 0; g2 < 16; ++g2) q += red[g2 * 64 + tid];
            atomicAdd(&stats[64 + tid], q);
        }
    }
}

// ===========================================================================
// Gather-aggregate in 64-dim + bias + relu:
//   mid[r] = relu((1+eps)*y[r] + sum_j w_j * y[src_j] + ba)
// ===========================================================================
__global__ __launch_bounds__(256) void aggmid_kernel(
    const float* __restrict__ y,
    const int* __restrict__ row_start,
    const uint2* __restrict__ einfo,
    const float* __restrict__ epsp,
    const float* __restrict__ ba,
    float* __restrict__ mid, int N)
{
    const int lane = threadIdx.x & 63;
    int w  = (blockIdx.x * 256 + threadIdx.x) >> 6;
    const int nw = (gridDim.x * 256) >> 6;
    const float eps1 = 1.0f + epsp[0];
    const float ba_l = ba[lane];

    for (int r = w; r < N; r += nw) {
        const int rs = row_start[r];
        const int re = row_start[r + 1];

        float a = 0.f, b = 0.f, c = 0.f, d = 0.f;
        int j = rs;
        for (; j + 4 <= re; j += 4) {
            uint2 p0 = einfo[j],     p1 = einfo[j + 1];
            uint2 p2 = einfo[j + 2], p3 = einfo[j + 3];
            float v0 = y[(size_t)p0.x * 64 + lane];
            float v1 = y[(size_t)p1.x * 64 + lane];
            float v2 = y[(size_t)p2.x * 64 + lane];
            float v3 = y[(size_t)p3.x * 64 + lane];
            a = fmaf(__uint_as_float(p0.y), v0, a);
            b = fmaf(__uint_as_float(p1.y), v1, b);
            c = fmaf(__uint_as_float(p2.y), v2, c);
            d = fmaf(__uint_as_float(p3.y), v3, d);
        }
        for (; j < re; ++j) {
            uint2 p = einfo[j];
            a = fmaf(__uint_as_float(p.y), y[(size_t)p.x * 64 + lane], a);
        }
        float v = fmaf(eps1, y[(size_t)r * 64 + lane], (a + b) + (c + d)) + ba_l;
        mid[(size_t)r * 64 + lane] = fmaxf(v, 0.f);
    }
}

// ===========================================================================
// BN finalize + apply
// ===========================================================================
__global__ void bn_finalize(const float* __restrict__ stats,
                            const float* __restrict__ g, const float* __restrict__ be,
                            float* __restrict__ ab, int N)
{
    int l = threadIdx.x;
    float invN = 1.0f / (float)N;
    float mean = stats[l] * invN;
    float var  = stats[64 + l] * invN - mean * mean;
    float a = g[l] * rsqrtf(var + BN_EPS);
    ab[l]      = a;
    ab[64 + l] = be[l] - mean * a;
}

template<int RES>
__global__ __launch_bounds__(256) void bn_apply(
    const float* __restrict__ h2, const float* __restrict__ ab,
    const float* res, float* out, int n4)   // res/out may alias (in-place)
{
    int i = blockIdx.x * blockDim.x + threadIdx.x;
    int stride = gridDim.x * blockDim.x;
    for (; i < n4; i += stride) {
        float4 v = reinterpret_cast<const float4*>(h2)[i];
        int l0 = (i * 4) & 63;
        float4 o;
        o.x = fmaxf(fmaf(v.x, ab[l0 + 0], ab[64 + l0 + 0]), 0.f);
        o.y = fmaxf(fmaf(v.y, ab[l0 + 1], ab[64 + l0 + 1]), 0.f);
        o.z = fmaxf(fmaf(v.z, ab[l0 + 2], ab[64 + l0 + 2]), 0.f);
        o.w = fmaxf(fmaf(v.w, ab[l0 + 3], ab[64 + l0 + 3]), 0.f);
        if (RES) {
            float4 rv = reinterpret_cast<const float4*>(res)[i];
            o.x += rv.x; o.y += rv.y; o.z += rv.z; o.w += rv.w;
        }
        reinterpret_cast<float4*>(out)[i] = o;
    }
}

// ===========================================================================
extern "C" void kernel_launch(void* const* d_in, const int* in_sizes, int n_in,
                              void* d_out, int out_size, void* d_ws, size_t ws_size,
                              hipStream_t stream)
{
    const float* x    = (const float*)d_in[0];
    const int*   ei   = (const int*)  d_in[1];
    const float* ew   = (const float*)d_in[2];
    const float* eps1 = (const float*)d_in[3];
    const float* W1a  = (const float*)d_in[4];
    const float* b1a  = (const float*)d_in[5];
    const float* W1b  = (const float*)d_in[6];
    const float* b1b  = (const float*)d_in[7];
    const float* g1   = (const float*)d_in[8];
    const float* be1  = (const float*)d_in[9];
    const float* epss = (const float*)d_in[10];
    const float* Wsa  = (const float*)d_in[11];
    const float* bsa  = (const float*)d_in[12];
    const float* Wsb  = (const float*)d_in[13];
    const float* bsb  = (const float*)d_in[14];
    const float* gs   = (const float*)d_in[15];
    const float* bes  = (const float*)d_in[16];

    const int N   = in_sizes[0] / 128;
    const int E   = in_sizes[2];
    const int Lm1 = in_sizes[10];
    const int* src  = ei;
    const int* dstp = ei + E;

    // ---- workspace layout ----
    char* ws = (char*)d_ws;
    size_t off = 0;
    uint2* einfo = (uint2*)(ws + off);   off += (size_t)E * 8;
    float* regA  = (float*)(ws + off);   off += (size_t)N * 128 * 4;  // bufX | bufY
    int*   rank  = (int*)  (ws + off);   off += (size_t)E * 4;
    int*   deg   = (int*)  (ws + off);   off += (size_t)N * 4;
    int*   row_start = (int*)(ws + off); off += (size_t)(N + 1) * 4;
    float* stats = (float*)(ws + off);   off += 128 * 4;
    float* ab    = (float*)(ws + off);   off += 128 * 4;
    int*   blockSums = (int*)(ws + off); off += 256 * 4;
    int*   blockOff  = (int*)(ws + off);
    float* outp  = (float*)d_out;
    float* bufX  = regA;                      // y / h2 scratch (N*64)
    float* bufY  = regA + (size_t)N * 64;     // mid scratch (N*64)

    const int n4   = N * 64 / 4;
    const int NB   = (N + 511) / 512;         // scan blocks
    const int NBLK = (N + 63) / 64;           // gemm row-tiles
    const int EB   = (E + 255) / 256;         // edge blocks (1 edge/thread)

    // ---- build CSR by dst (once per call, reused by all layers) ----
    hipMemsetAsync(deg, 0, (size_t)N * 4, stream);
    rank_kernel<<<EB, 256, 0, stream>>>(dstp, deg, rank, E);
    scan_part1<<<NB, 256, 0, stream>>>(deg, blockSums, N);
    scan_part2<<<1, 256, 0, stream>>>(blockSums, blockOff, NB);
    scan_part3<<<NB, 256, 0, stream>>>(deg, blockOff, row_start, N, E);
    fill_pass2<<<EB, 256, 0, stream>>>(src, dstp, ew, rank, row_start, einfo, E);

    // ---- layer 1 (F=128 -> 64): y = x@W1a first (linearity), gather in 64-dim
    gemm64_kernel<128, false><<<NBLK, 256, 0, stream>>>(x, W1a, nullptr, bufX, nullptr, N);
    aggmid_kernel<<<2048, 256, 0, stream>>>(bufX, row_start, einfo, eps1, b1a, bufY, N);
    hipMemsetAsync(stats, 0, 128 * 4, stream);
    gemm64_kernel<64, true><<<NBLK, 256, 0, stream>>>(bufY, W1b, b1b, bufX, stats, N);
    bn_finalize<<<1, 64, 0, stream>>>(stats, g1, be1, ab, N);
    bn_apply<0><<<2048, 256, 0, stream>>>(bufX, ab, nullptr, outp, n4);

    // ---- layers 2..L (64 -> 64, residual, in-place over outp) ----
    for (int i = 0; i < Lm1; ++i) {
        gemm64_kernel<64, false><<<NBLK, 256, 0, stream>>>(
            outp, Wsa + (size_t)i * 64 * 64, nullptr, bufX, nullptr, N);
        aggmid_kernel<<<2048, 256, 0, stream>>>(
            bufX, row_start, einfo, epss + i, bsa + (size_t)i * 64, bufY, N);
        hipMemsetAsync(stats, 0, 128 * 4, stream);
        gemm64_kernel<64, true><<<NBLK, 256, 0, stream>>>(
            bufY, Wsb + (size_t)i * 64 * 64, bsb + (size_t)i * 64, bufX, stats, N);
        bn_finalize<<<1, 64, 0, stream>>>(stats, gs + (size_t)i * 64, bes + (size_t)i * 64, ab, N);
        bn_apply<1><<<2048, 256, 0, stream>>>(bufX, ab, outp, outp, n4);  // in-place residual
    }
}

// Round 9
// 559.529 us; speedup vs baseline: 4.1574x; 1.1391x over previous
//
#include <hip/hip_runtime.h>

#define BN_EPS 1e-5f

// bf16 bit helpers (ROCm's __hip_bfloat16 API varies; use raw ushort)
__device__ __forceinline__ unsigned short f32_to_bf16(float f) {
    unsigned u = __float_as_uint(f);
    u += 0x7fffu + ((u >> 16) & 1u);   // round to nearest even
    return (unsigned short)(u >> 16);
}
__device__ __forceinline__ float bf16_to_f32(unsigned short h) {
    return __uint_as_float((unsigned)h << 16);
}

// ===========================================================================
// CSR construction (by dst): rank pass -> 3-phase scan -> atomic-free fill
// ===========================================================================
__global__ __launch_bounds__(256) void rank_kernel(
    const int* __restrict__ dst, int* __restrict__ deg,
    int* __restrict__ rank, int E)
{
    int i = blockIdx.x * 256 + threadIdx.x;
    if (i < E) rank[i] = atomicAdd(&deg[dst[i]], 1);
}

__global__ __launch_bounds__(256) void scan_part1(
    const int* __restrict__ deg, int* __restrict__ blockSums, int N)
{
    __shared__ int sm[256];
    int t = threadIdx.x;
    int i0 = blockIdx.x * 512 + t * 2;
    int a = (i0     < N) ? deg[i0]     : 0;
    int b = (i0 + 1 < N) ? deg[i0 + 1] : 0;
    sm[t] = a + b;
    __syncthreads();
    for (int off = 128; off > 0; off >>= 1) {
        if (t < off) sm[t] += sm[t + off];
        __syncthreads();
    }
    if (t == 0) blockSums[blockIdx.x] = sm[0];
}

__global__ __launch_bounds__(256) void scan_part2(
    const int* __restrict__ blockSums, int* __restrict__ blockOff, int NB)
{
    __shared__ int sm[256];
    int t = threadIdx.x;
    sm[t] = (t < NB) ? blockSums[t] : 0;
    __syncthreads();
    for (int off = 1; off < 256; off <<= 1) {
        int v = (t >= off) ? sm[t - off] : 0;
        __syncthreads();
        sm[t] += v;
        __syncthreads();
    }
    if (t < NB) blockOff[t] = (t > 0) ? sm[t - 1] : 0;
}

__global__ __launch_bounds__(256) void scan_part3(
    const int* __restrict__ deg, const int* __restrict__ blockOff,
    int* __restrict__ row_start, int N, int E)
{
    __shared__ int sm[256];
    int t = threadIdx.x;
    int i0 = blockIdx.x * 512 + t * 2;
    int a = (i0     < N) ? deg[i0]     : 0;
    int b = (i0 + 1 < N) ? deg[i0 + 1] : 0;
    sm[t] = a + b;
    __syncthreads();
    for (int off = 1; off < 256; off <<= 1) {
        int v = (t >= off) ? sm[t - off] : 0;
        __syncthreads();
        sm[t] += v;
        __syncthreads();
    }
    int excl = blockOff[blockIdx.x] + ((t > 0) ? sm[t - 1] : 0);
    if (i0 < N)     row_start[i0]     = excl;
    if (i0 + 1 < N) row_start[i0 + 1] = excl + a;
    if (blockIdx.x == 0 && t == 0) row_start[N] = E;
}

__global__ __launch_bounds__(256) void fill_pass2(
    const int* __restrict__ src, const int* __restrict__ dst,
    const float* __restrict__ ew, const int* __restrict__ rank,
    const int* __restrict__ row_start, uint2* __restrict__ einfo, int E)
{
    int i = blockIdx.x * 256 + threadIdx.x;
    if (i < E) {
        int pos = row_start[dst[i]] + rank[i];
        uint2 p;
        p.x = (unsigned)src[i];
        p.y = __float_as_uint(ew[i]);
        einfo[pos] = p;
    }
}

// ===========================================================================
// Register-tiled GEMM: out[N][64] = A[N][K] @ W[K][64] (+bias)
// 256 thr, 64-row tile, 4x4 per thread. BF16OUT: store as bf16 gather table.
// ===========================================================================
template<int K, bool BF16OUT>
__global__ __launch_bounds__(256) void gemm64_kernel(
    const float* __restrict__ A, const float* __restrict__ W,
    const float* __restrict__ bias, void* __restrict__ out, int N)
{
    __shared__ float sA[64][K];
    __shared__ float sW[K][64];

    const int tid = threadIdx.x;
    const int r0  = blockIdx.x * 64;
    constexpr int C4 = K / 4;

    for (int i = tid; i < K * 16; i += 256)
        reinterpret_cast<float4*>(&sW[0][0])[i] =
            reinterpret_cast<const float4*>(W)[i];
    for (int i = tid; i < 64 * C4; i += 256) {
        int r  = i / C4;
        int c4 = i % C4;
        float4 v = make_float4(0.f, 0.f, 0.f, 0.f);
        if (r0 + r < N)
            v = reinterpret_cast<const float4*>(A + (size_t)(r0 + r) * K)[c4];
        reinterpret_cast<float4*>(&sA[r][0])[c4] = v;
    }
    __syncthreads();

    const int rr = (tid >> 4) * 4;
    const int cc = (tid & 15) * 4;

    float4 bv = make_float4(0.f, 0.f, 0.f, 0.f);
    if (bias) bv = *reinterpret_cast<const float4*>(bias + cc);

    float acc[4][4];
    #pragma unroll
    for (int i = 0; i < 4; ++i) {
        acc[i][0] = bv.x; acc[i][1] = bv.y; acc[i][2] = bv.z; acc[i][3] = bv.w;
    }

    #pragma unroll 2
    for (int k = 0; k < K; k += 4) {
        float4 w0 = *reinterpret_cast<const float4*>(&sW[k + 0][cc]);
        float4 w1 = *reinterpret_cast<const float4*>(&sW[k + 1][cc]);
        float4 w2 = *reinterpret_cast<const float4*>(&sW[k + 2][cc]);
        float4 w3 = *reinterpret_cast<const float4*>(&sW[k + 3][cc]);
        #pragma unroll
        for (int i = 0; i < 4; ++i) {
            float4 av = *reinterpret_cast<const float4*>(&sA[rr + i][k]);
            acc[i][0] = fmaf(av.x, w0.x, fmaf(av.y, w1.x, fmaf(av.z, w2.x, fmaf(av.w, w3.x, acc[i][0]))));
            acc[i][1] = fmaf(av.x, w0.y, fmaf(av.y, w1.y, fmaf(av.z, w2.y, fmaf(av.w, w3.y, acc[i][1]))));
            acc[i][2] = fmaf(av.x, w0.z, fmaf(av.y, w1.z, fmaf(av.z, w2.z, fmaf(av.w, w3.z, acc[i][2]))));
            acc[i][3] = fmaf(av.x, w0.w, fmaf(av.y, w1.w, fmaf(av.z, w2.w, fmaf(av.w, w3.w, acc[i][3]))));
        }
    }

    #pragma unroll
    for (int i = 0; i < 4; ++i) {
        int r = r0 + rr + i;
        if (r < N) {
            if (BF16OUT) {
                ushort4 o;
                o.x = f32_to_bf16(acc[i][0]);
                o.y = f32_to_bf16(acc[i][1]);
                o.z = f32_to_bf16(acc[i][2]);
                o.w = f32_to_bf16(acc[i][3]);
                *reinterpret_cast<ushort4*>((unsigned short*)out + (size_t)r * 64 + cc) = o;
            } else {
                float4 o = make_float4(acc[i][0], acc[i][1], acc[i][2], acc[i][3]);
                *reinterpret_cast<float4*>((float*)out + (size_t)r * 64 + cc) = o;
            }
        }
    }
}

// ===========================================================================
// BN stats: per-column sum / sumsq over N rows (streaming, conflict-free)
// ===========================================================================
__global__ __launch_bounds__(256) void bn_stats_kernel(
    const float* __restrict__ h2, float* __restrict__ stats, int N)
{
    __shared__ float red[2][4][64];
    const int col = threadIdx.x & 63;
    const int w   = threadIdx.x >> 6;
    int r = blockIdx.x * 4 + w;
    const int rstride = gridDim.x * 4;
    float s = 0.f, q = 0.f;
    for (; r < N; r += rstride) {
        float v = h2[(size_t)r * 64 + col];
        s += v; q += v * v;
    }
    red[0][w][col] = s;
    red[1][w][col] = q;
    __syncthreads();
    if (w == 0) {
        float ss = red[0][0][col] + red[0][1][col] + red[0][2][col] + red[0][3][col];
        float qq = red[1][0][col] + red[1][1][col] + red[1][2][col] + red[1][3][col];
        atomicAdd(&stats[col],      ss);
        atomicAdd(&stats[64 + col], qq);
    }
}

// ===========================================================================
// Gather-aggregate (bf16 table) + bias + relu:
//   mid[r] = relu((1+eps)*y[r] + sum_j w_j * y[src_j] + ba)   (mid f32)
// ===========================================================================
__global__ __launch_bounds__(256) void aggmid_kernel(
    const unsigned short* __restrict__ y,
    const int* __restrict__ row_start,
    const uint2* __restrict__ einfo,
    const float* __restrict__ epsp,
    const float* __restrict__ ba,
    float* __restrict__ mid, int N)
{
    const int lane = threadIdx.x & 63;
    int w  = (blockIdx.x * 256 + threadIdx.x) >> 6;
    const int nw = (gridDim.x * 256) >> 6;
    const float eps1 = 1.0f + epsp[0];
    const float ba_l = ba[lane];

    for (int r = w; r < N; r += nw) {
        const int rs = row_start[r];
        const int re = row_start[r + 1];

        float a = 0.f, b = 0.f, c = 0.f, d = 0.f;
        int j = rs;
        for (; j + 4 <= re; j += 4) {
            uint2 p0 = einfo[j],     p1 = einfo[j + 1];
            uint2 p2 = einfo[j + 2], p3 = einfo[j + 3];
            float v0 = bf16_to_f32(y[(size_t)p0.x * 64 + lane]);
            float v1 = bf16_to_f32(y[(size_t)p1.x * 64 + lane]);
            float v2 = bf16_to_f32(y[(size_t)p2.x * 64 + lane]);
            float v3 = bf16_to_f32(y[(size_t)p3.x * 64 + lane]);
            a = fmaf(__uint_as_float(p0.y), v0, a);
            b = fmaf(__uint_as_float(p1.y), v1, b);
            c = fmaf(__uint_as_float(p2.y), v2, c);
            d = fmaf(__uint_as_float(p3.y), v3, d);
        }
        for (; j < re; ++j) {
            uint2 p = einfo[j];
            a = fmaf(__uint_as_float(p.y), bf16_to_f32(y[(size_t)p.x * 64 + lane]), a);
        }
        float self = bf16_to_f32(y[(size_t)r * 64 + lane]);
        float v = fmaf(eps1, self, (a + b) + (c + d)) + ba_l;
        mid[(size_t)r * 64 + lane] = fmaxf(v, 0.f);
    }
}

// ===========================================================================
// BN finalize + apply
// ===========================================================================
__global__ void bn_finalize(const float* __restrict__ stats,
                            const float* __restrict__ g, const float* __restrict__ be,
                            float* __restrict__ ab, int N)
{
    int l = threadIdx.x;
    float invN = 1.0f / (float)N;
    float mean = stats[l] * invN;
    float var  = stats[64 + l] * invN - mean * mean;
    float a = g[l] * rsqrtf(var + BN_EPS);
    ab[l]      = a;
    ab[64 + l] = be[l] - mean * a;
}

template<int RES>
__global__ __launch_bounds__(256) void bn_apply(
    const float* __restrict__ h2, const float* __restrict__ ab,
    const float* res, float* out, int n4)   // res/out may alias (in-place)
{
    int i = blockIdx.x * blockDim.x + threadIdx.x;
    int stride = gridDim.x * blockDim.x;
    for (; i < n4; i += stride) {
        float4 v = reinterpret_cast<const float4*>(h2)[i];
        int l0 = (i * 4) & 63;
        float4 o;
        o.x = fmaxf(fmaf(v.x, ab[l0 + 0], ab[64 + l0 + 0]), 0.f);
        o.y = fmaxf(fmaf(v.y, ab[l0 + 1], ab[64 + l0 + 1]), 0.f);
        o.z = fmaxf(fmaf(v.z, ab[l0 + 2], ab[64 + l0 + 2]), 0.f);
        o.w = fmaxf(fmaf(v.w, ab[l0 + 3], ab[64 + l0 + 3]), 0.f);
        if (RES) {
            float4 rv = reinterpret_cast<const float4*>(res)[i];
            o.x += rv.x; o.y += rv.y; o.z += rv.z; o.w += rv.w;
        }
        reinterpret_cast<float4*>(out)[i] = o;
    }
}

// ===========================================================================
extern "C" void kernel_launch(void* const* d_in, const int* in_sizes, int n_in,
                              void* d_out, int out_size, void* d_ws, size_t ws_size,
                              hipStream_t stream)
{
    const float* x    = (const float*)d_in[0];
    const int*   ei   = (const int*)  d_in[1];
    const float* ew   = (const float*)d_in[2];
    const float* eps1 = (const float*)d_in[3];
    const float* W1a  = (const float*)d_in[4];
    const float* b1a  = (const float*)d_in[5];
    const float* W1b  = (const float*)d_in[6];
    const float* b1b  = (const float*)d_in[7];
    const float* g1   = (const float*)d_in[8];
    const float* be1  = (const float*)d_in[9];
    const float* epss = (const float*)d_in[10];
    const float* Wsa  = (const float*)d_in[11];
    const float* bsa  = (const float*)d_in[12];
    const float* Wsb  = (const float*)d_in[13];
    const float* bsb  = (const float*)d_in[14];
    const float* gs   = (const float*)d_in[15];
    const float* bes  = (const float*)d_in[16];

    const int N   = in_sizes[0] / 128;
    const int E   = in_sizes[2];
    const int Lm1 = in_sizes[10];
    const int* src  = ei;
    const int* dstp = ei + E;

    // ---- workspace layout ----
    char* ws = (char*)d_ws;
    size_t off = 0;
    uint2* einfo = (uint2*)(ws + off);   off += (size_t)E * 8;
    float* regA  = (float*)(ws + off);   off += (size_t)N * 128 * 4;  // bufX | bufY
    unsigned short* ybf = (unsigned short*)(ws + off); off += (size_t)N * 64 * 2;
    int*   rank  = (int*)  (ws + off);   off += (size_t)E * 4;
    int*   deg   = (int*)  (ws + off);   off += (size_t)N * 4;
    int*   row_start = (int*)(ws + off); off += (size_t)(N + 1) * 4;
    float* stats = (float*)(ws + off);   off += 128 * 4;
    float* ab    = (float*)(ws + off);   off += 128 * 4;
    int*   blockSums = (int*)(ws + off); off += 256 * 4;
    int*   blockOff  = (int*)(ws + off);
    float* outp  = (float*)d_out;
    float* bufX  = regA;                      // mid scratch (N*64 f32)
    float* bufY  = regA + (size_t)N * 64;     // h2 scratch (N*64 f32)

    const int n4   = N * 64 / 4;
    const int NB   = (N + 511) / 512;         // scan blocks
    const int NBLK = (N + 63) / 64;           // gemm row-tiles
    const int EB   = (E + 255) / 256;         // edge blocks (1 edge/thread)

    // ---- build CSR by dst (once per call, reused by all layers) ----
    hipMemsetAsync(deg, 0, (size_t)N * 4, stream);
    rank_kernel<<<EB, 256, 0, stream>>>(dstp, deg, rank, E);
    scan_part1<<<NB, 256, 0, stream>>>(deg, blockSums, N);
    scan_part2<<<1, 256, 0, stream>>>(blockSums, blockOff, NB);
    scan_part3<<<NB, 256, 0, stream>>>(deg, blockOff, row_start, N, E);
    fill_pass2<<<EB, 256, 0, stream>>>(src, dstp, ew, rank, row_start, einfo, E);

    // ---- layer 1 (F=128 -> 64): y = x@W1a (bf16), gather, mid@W1b, BN
    gemm64_kernel<128, true><<<NBLK, 256, 0, stream>>>(x, W1a, nullptr, ybf, N);
    aggmid_kernel<<<2048, 256, 0, stream>>>(ybf, row_start, einfo, eps1, b1a, bufX, N);
    gemm64_kernel<64, false><<<NBLK, 256, 0, stream>>>(bufX, W1b, b1b, bufY, N);
    hipMemsetAsync(stats, 0, 128 * 4, stream);
    bn_stats_kernel<<<512, 256, 0, stream>>>(bufY, stats, N);
    bn_finalize<<<1, 64, 0, stream>>>(stats, g1, be1, ab, N);
    bn_apply<0><<<2048, 256, 0, stream>>>(bufY, ab, nullptr, outp, n4);

    // ---- layers 2..L (64 -> 64, residual, in-place over outp) ----
    for (int i = 0; i < Lm1; ++i) {
        gemm64_kernel<64, true><<<NBLK, 256, 0, stream>>>(
            outp, Wsa + (size_t)i * 64 * 64, nullptr, ybf, N);
        aggmid_kernel<<<2048, 256, 0, stream>>>(
            ybf, row_start, einfo, epss + i, bsa + (size_t)i * 64, bufX, N);
        gemm64_kernel<64, false><<<NBLK, 256, 0, stream>>>(
            bufX, Wsb + (size_t)i * 64 * 64, bsb + (size_t)i * 64, bufY, N);
        hipMemsetAsync(stats, 0, 128 * 4, stream);
        bn_stats_kernel<<<512, 256, 0, stream>>>(bufY, stats, N);
        bn_finalize<<<1, 64, 0, stream>>>(stats, gs + (size_t)i * 64, bes + (size_t)i * 64, ab, N);
        bn_apply<1><<<2048, 256, 0, stream>>>(bufY, ab, outp, outp, n4);  // in-place residual
    }
}